// Round 4
// baseline (209.854 us; speedup 1.0000x reference)
//
#include <hip/hip_runtime.h>
#include <cmath>

typedef __attribute__((ext_vector_type(8))) short bf16x8;
typedef __attribute__((ext_vector_type(4))) float f32x4;
typedef __attribute__((ext_vector_type(16))) float f32x16;

#define MFMA16(a,b,c)  __builtin_amdgcn_mfma_f32_16x16x32_bf16((a),(b),(c),0,0,0)
#define MFMA32(a,b,c)  __builtin_amdgcn_mfma_f32_32x32x16_bf16((a),(b),(c),0,0,0)

#if __has_builtin(__builtin_amdgcn_exp2f)
#define EXP2F(x) __builtin_amdgcn_exp2f(x)
#else
#define EXP2F(x) exp2f(x)
#endif

// sqrt(128) * log2(e): folded into w_theta/b_theta at wcvt time.
#define KSCALE 16.3222312f

#define NB 4
#define CH 256
#define CI 128
#define NS 4096   // 64*64 spatial
#define SPLIT 8

__device__ __forceinline__ unsigned short f2bf(float f) {
    unsigned int u = __builtin_bit_cast(unsigned int, f);
    u += 0x7fffu + ((u >> 16) & 1u);           // RNE
    return (unsigned short)(u >> 16);
}
__device__ __forceinline__ unsigned int pk2(float lo, float hi) {
    return (unsigned int)f2bf(lo) | ((unsigned int)f2bf(hi) << 16);
}
// truncating pack (softmax P only): 1-op v_perm_b32
__device__ __forceinline__ unsigned int pkt(float lo, float hi) {
    return __builtin_amdgcn_perm(__builtin_bit_cast(unsigned int, hi),
                                 __builtin_bit_cast(unsigned int, lo), 0x07060302u);
}
__device__ __forceinline__ float bf2f(unsigned int ush) {   // low 16 bits
    return __builtin_bit_cast(float, ush << 16);
}

// Half-exchange for P-fragment assembly (verified R3).
// Call as plswap(wLow, wHigh):
//   in : wLow  = even-g word, lane-half h holds s16 (4h+m0, 4h+m0+1)
//        wHigh = odd-g  word, lane-half h holds s16 (8+4h+m0, 8+4h+m0+1)
//   out: wLow  = fragment k-low word, wHigh = fragment k-high word
__device__ __forceinline__ void plswap(unsigned int& wLow, unsigned int& wHigh) {
    asm volatile("v_permlane32_swap_b32 %0, %1" : "+v"(wLow), "+v"(wHigh));
}

__device__ __forceinline__ f32x16 zero16() {
    f32x16 v;
#pragma unroll
    for (int i = 0; i < 16; i++) v[i] = 0.f;
    return v;
}

// async global->LDS 16B per lane: LDS dest = wave-uniform base + lane*16
__device__ __forceinline__ void gload16(void* lds, const void* g) {
    __builtin_amdgcn_global_load_lds(
        (const __attribute__((address_space(1))) unsigned int*)g,
        (__attribute__((address_space(3))) unsigned int*)lds,
        16, 0, 0);
}

// ---------------------------------------------------------------------------
// Kernel 0: one-time weight convert to bf16 (KSCALE folded into theta).
// ---------------------------------------------------------------------------
__global__ void wcvt_kernel(const float* __restrict__ w_g, const float* __restrict__ w_th,
                            const float* __restrict__ w_ph, const float* __restrict__ w_out,
                            const float* __restrict__ b_g, const float* __restrict__ b_th,
                            const float* __restrict__ b_ph,
                            unsigned short* __restrict__ wbf, float* __restrict__ bsc) {
    int i = blockIdx.x * 256 + threadIdx.x;     // 0..131071
    float v;
    if (i < 32768)        v = w_g[i];
    else if (i < 65536)   v = w_th[i - 32768] * KSCALE;
    else if (i < 98304)   v = w_ph[i - 65536];
    else                  v = w_out[i - 98304];
    wbf[i] = f2bf(v);
    if (i < 128)          bsc[i] = b_g[i];
    else if (i < 256)     bsc[i] = b_th[i - 128] * KSCALE;
    else if (i < 384)     bsc[i] = b_ph[i - 256];
}

// ---------------------------------------------------------------------------
// Kernel 1: FUSED projections — one x staging serves g/theta/phi (x read 1x).
// grid(64 s-tiles of 64, 4 n) = 256 blocks, 512 thr (8 waves).
// ---------------------------------------------------------------------------
__global__ __launch_bounds__(512, 2)
void proj_kernel(const float* __restrict__ x,
                 const unsigned short* __restrict__ wbf, const float* __restrict__ bsc,
                 unsigned short* __restrict__ theta,
                 unsigned short* __restrict__ phi,
                 unsigned short* __restrict__ gT) {
    const int tid  = threadIdx.x;
    const int wid  = tid >> 6;         // 0..7
    const int lane = tid & 63;
    const int quad = lane >> 4;
    const int l15  = lane & 15;
    const int stile = blockIdx.x;      // 0..63
    const int n     = blockIdx.y;
    const int s0    = stile * 64;

    const float* xN = x + (size_t)n * CH * NS;

    __shared__ unsigned int xp[64 * 128];   // 32 KB, swizzled

    // stage: 2048 tasks (128 c-pairs x 16 s-spans of float4), 4/thread
#pragma unroll
    for (int i = 0; i < 4; i++) {
        int t  = i * 512 + tid;
        int s4 = t & 15;
        int cp = t >> 4;                    // 0..127
        const float* p0 = xN + (size_t)(2 * cp) * NS + s0 + s4 * 4;
        float4 a = *(const float4*)p0;
        float4 b = *(const float4*)(p0 + NS);
        int col = (((cp >> 2) ^ (s4 & 7)) << 2) | (cp & 3);   // row>>2 == s4
        unsigned int* xr = xp + (s4 * 4) * 128 + col;
        xr[0]   = pk2(a.x, b.x);
        xr[128] = pk2(a.y, b.y);
        xr[256] = pk2(a.z, b.z);
        xr[384] = pk2(a.w, b.w);
    }
    __syncthreads();

    const int srow = (wid & 3) * 16 + l15;
    const int oh   = wid >> 2;              // o-half
    const int sw7  = (srow >> 2) & 7;
#pragma unroll
    for (int wi = 0; wi < 3; wi++) {
        f32x4 acc[4];
#pragma unroll
        for (int ot = 0; ot < 4; ot++) acc[ot] = (f32x4){0.f, 0.f, 0.f, 0.f};
        const unsigned short* W = wbf + (size_t)wi * 32768 + (size_t)oh * 64 * CH;
#pragma unroll
        for (int kc = 0; kc < 8; kc++) {
            bf16x8 af = *(const bf16x8*)(&xp[srow * 128 + (((kc * 4 + quad) ^ sw7) << 2)]);
#pragma unroll
            for (int ot = 0; ot < 4; ot++) {
                bf16x8 wf = *(const bf16x8*)(W + (size_t)(ot * 16 + l15) * CH + kc * 32 + quad * 8);
                acc[ot] = MFMA16(af, wf, acc[ot]);
            }
        }
        const float* Bv = bsc + wi * 128 + oh * 64;
#pragma unroll
        for (int ot = 0; ot < 4; ot++) {
            int o = oh * 64 + ot * 16 + l15;
            float bias = Bv[ot * 16 + l15];
#pragma unroll
            for (int r = 0; r < 4; r++) {
                int sg = s0 + (wid & 3) * 16 + quad * 4 + r;
                float v = acc[ot][r] + bias;
                if (wi == 0)
                    gT[((size_t)n * CI + o) * NS + sg] = f2bf(v);
                else if (wi == 1)
                    theta[((size_t)n * NS + sg) * CI + o] = f2bf(v);
                else
                    phi[((size_t)n * NS + sg) * CI + o] = f2bf(v);
            }
        }
    }
}

// ---------------------------------------------------------------------------
// Kernel 2: flash attention partials — q=64/wave (two 32-q MFMA tiles).
// LDS-throughput-bound fix: each kf/vf ds_read_b128 now feeds TWO q-tiles'
// MFMAs -> LDS reads per q halve (R3 model: LDS pipe 24us/CU dominant).
// 256 thr (4 waves x 64 q = 256 q/block), 64-s chunks, split=8 (8 chunks),
// K/V double-buffer, 64 KB LDS -> 2 blocks/CU, 8 waves/CU.
// Register plan (<=256 VGPR): O 2x4xf32x16=128, qf 2x8xbf16x8=64,
// per-sb S 2xf32x16=32, pf 4xbf16x8=16 — processed per 32-s sub-block.
// grid(32 = split*4+n, 16 qb) = 512 blocks.
// ---------------------------------------------------------------------------
__global__ __launch_bounds__(256, 2)
void attn_kernel(const unsigned short* __restrict__ theta,
                 const unsigned short* __restrict__ phi,
                 const unsigned short* __restrict__ gT,
                 unsigned short* __restrict__ Opart,
                 float* __restrict__ lbuf) {
    const int tid  = threadIdx.x;
    const int wid  = tid >> 6;          // 0..3
    const int lane = tid & 63;
    const int l31  = lane & 31;
    const int lh32 = lane >> 5;         // 0..1
    const int sn    = blockIdx.x;       // 0..31
    const int split = sn >> 2;          // 0..7
    const int n     = sn & 3;
    const int qb    = blockIdx.y;       // 0..15
    const int qbase = qb * 256 + wid * 64;

    const unsigned short* thN = theta + (size_t)n * NS * CI;
    const unsigned short* phN = phi   + (size_t)n * NS * CI;
    const unsigned short* gN  = gT    + (size_t)n * CI * NS;

    // K dbuf: 2 x [64 s][128 c] (slot ^ (s&15))   32 KB
    // V dbuf: 2 x [128 c][64 s] (slot ^ (c&7))    32 KB     total 64 KB
    __shared__ unsigned short smem[32768];
    unsigned short* Kb = smem;              // + cur*8192
    unsigned short* Vb = smem + 16384;      // + cur*8192

    // Q B-fragments, 2 q-tiles: col q = qt*32 + l31, k = lh32*8 + e per slice
    bf16x8 qf[2][8];
#pragma unroll
    for (int qt = 0; qt < 2; qt++)
#pragma unroll
        for (int kc = 0; kc < 8; kc++)
            qf[qt][kc] = *(const bf16x8*)(thN + (size_t)(qbase + qt * 32 + l31) * CI + kc * 16 + lh32 * 8);

    f32x16 O[2][4];   // [qt][ct]: row c = ct*32+(reg&3)+8*(reg>>2)+4*lh32, col q
#pragma unroll
    for (int qt = 0; qt < 2; qt++)
#pragma unroll
        for (int ct = 0; ct < 4; ct++) O[qt][ct] = zero16();
    float lrun[2] = {0.f, 0.f};

    const int sbase0 = split * 512;
    const int lh16 = lane >> 4, lm16 = lane & 15;
    const int lh8  = lane >> 3, lm8  = lane & 7;

    // stage chunk 0 -> buffer 0 (4 K segs + 4 V segs per wave)
#pragma unroll
    for (int i = 0; i < 4; i++) {
        int seg = wid * 4 + i;                  // 0..15
        int s   = seg * 4 + lh16;               // 0..63
        int j   = lm16 ^ (s & 15);
        gload16(Kb + seg * 512, phN + (size_t)(sbase0 + s) * CI + j * 8);
    }
#pragma unroll
    for (int i = 0; i < 4; i++) {
        int seg = wid * 4 + i;
        int c   = seg * 8 + lh8;                // 0..127
        int j   = lm8 ^ (c & 7);
        gload16(Vb + seg * 512, gN + (size_t)c * NS + sbase0 + j * 8);
    }

    for (int ck = 0; ck < 8; ck++) {
        const int cur = ck & 1, nxt = cur ^ 1;
        unsigned short* Kc = Kb + cur * 8192;
        unsigned short* Vc = Vb + cur * 8192;
        __syncthreads();    // drains cur loads; prev compute done

        if (ck + 1 < 8) {   // async prefetch next chunk
            const int sb1 = sbase0 + (ck + 1) * 64;
#pragma unroll
            for (int i = 0; i < 4; i++) {
                int seg = wid * 4 + i;
                int s   = seg * 4 + lh16;
                int j   = lm16 ^ (s & 15);
                gload16(Kb + nxt * 8192 + seg * 512, phN + (size_t)(sb1 + s) * CI + j * 8);
            }
#pragma unroll
            for (int i = 0; i < 4; i++) {
                int seg = wid * 4 + i;
                int c   = seg * 8 + lh8;
                int j   = lm8 ^ (c & 7);
                gload16(Vb + nxt * 8192 + seg * 512, gN + (size_t)c * NS + sb1 + j * 8);
            }
        }

        // two 32-s sub-blocks: QK^T -> softmax -> PV (keeps S live only per-sb)
#pragma unroll
        for (int sb = 0; sb < 2; sb++) {
            // QK^T: one kf read feeds both q-tiles
            f32x16 S0 = zero16(), S1 = zero16();
            __builtin_amdgcn_s_setprio(1);
#pragma unroll
            for (int kc = 0; kc < 8; kc++) {
                int s = sb * 32 + l31;
                bf16x8 kf = *(const bf16x8*)(Kc + s * 128 + (((kc * 2 + lh32) ^ (s & 15)) * 8));
                S0 = MFMA32(kf, qf[0][kc], S0);
                S1 = MFMA32(kf, qf[1][kc], S1);
            }
            __builtin_amdgcn_s_setprio(0);

            // softmax: p = exp2(S); P B-fragments (k=s) per 16-s slice b.
            bf16x8 pf[2][2];   // [qt][b]
#pragma unroll
            for (int qt = 0; qt < 2; qt++) {
                const f32x16& S = qt ? S1 : S0;
                float lsum = 0.f;
#pragma unroll
                for (int b = 0; b < 2; b++) {
                    float pA[4], pB[4];
#pragma unroll
                    for (int m = 0; m < 4; m++) {
                        pA[m] = EXP2F(S[(2 * b) * 4 + m]);       // even g: s16 = m+4h
                        pB[m] = EXP2F(S[(2 * b + 1) * 4 + m]);   // odd g:  s16 = 8+m+4h
                    }
                    lsum += ((pA[0] + pA[1]) + (pA[2] + pA[3]))
                          + ((pB[0] + pB[1]) + (pB[2] + pB[3]));
                    unsigned int wA0 = pkt(pA[0], pA[1]);
                    unsigned int wA1 = pkt(pA[2], pA[3]);
                    unsigned int wB0 = pkt(pB[0], pB[1]);
                    unsigned int wB1 = pkt(pB[2], pB[3]);
                    plswap(wA0, wB0);   // wA0 -> u0, wB0 -> u2
                    plswap(wA1, wB1);   // wA1 -> u1, wB1 -> u3
                    union { unsigned int u[4]; bf16x8 v; } P;
                    P.u[0] = wA0; P.u[1] = wA1; P.u[2] = wB0; P.u[3] = wB1;
                    pf[qt][b] = P.v;
                }
                lrun[qt] += lsum;
            }

            // PV: one vf read feeds both q-tiles
            __builtin_amdgcn_s_setprio(1);
#pragma unroll
            for (int b = 0; b < 2; b++) {
                const int ks = sb * 2 + b;
#pragma unroll
                for (int ct = 0; ct < 4; ct++) {
                    int c = ct * 32 + l31;
                    bf16x8 vf = *(const bf16x8*)(Vc + c * 64 + (((ks * 2 + lh32) ^ (c & 7)) * 8));
                    O[0][ct] = MFMA32(vf, pf[0][b], O[0][ct]);
                    O[1][ct] = MFMA32(vf, pf[1][b], O[1][ct]);
                }
            }
            __builtin_amdgcn_s_setprio(0);
        }
    }

    // epilogue: O^T (32x32 tiles) -> Opart[q][c] bf16 via per-wave LDS
    // transpose; per qt: 2 passes of 2 ct (8 KB tb per wave), XOR-swizzled.
    __syncthreads();
    float* tb = (float*)smem + wid * 2048;   // 4 waves x 8 KB
    const size_t obase = ((size_t)(split * NB + n)) * NS * CI;
#pragma unroll
    for (int qt = 0; qt < 2; qt++) {
#pragma unroll
        for (int pass = 0; pass < 2; pass++) {
#pragma unroll
            for (int cti = 0; cti < 2; cti++) {
                const int ct = pass * 2 + cti;
#pragma unroll
                for (int g = 0; g < 4; g++) {
                    const int c_local = cti * 32 + 8 * g + 4 * lh32;   // +0..3
                    const int slot = (c_local >> 2) ^ (l31 & 15);
                    f32x4 v;
                    v[0] = O[qt][ct][4 * g + 0]; v[1] = O[qt][ct][4 * g + 1];
                    v[2] = O[qt][ct][4 * g + 2]; v[3] = O[qt][ct][4 * g + 3];
                    *(f32x4*)(tb + l31 * 64 + slot * 4) = v;
                }
            }
#pragma unroll
            for (int i = 0; i < 8; i++) {
                const int qr  = i * 4 + (lane >> 4);    // 0..31
                const int lin = lane & 15;
                f32x4 v = *(const f32x4*)(tb + qr * 64 + ((lin ^ (qr & 15)) * 4));
                uint2 w;
                w.x = pk2(v[0], v[1]);
                w.y = pk2(v[2], v[3]);
                *(uint2*)(Opart + obase + (size_t)(qbase + qt * 32 + qr) * CI + pass * 64 + lin * 4) = w;
            }
        }
    }
    lrun[0] += __shfl_xor(lrun[0], 32);
    lrun[1] += __shfl_xor(lrun[1], 32);
    if (lane < 32) {
        lbuf[(split * NB + n) * NS + qbase + l31]      = lrun[0];
        lbuf[(split * NB + n) * NS + qbase + 32 + l31] = lrun[1];
    }
}

// ---------------------------------------------------------------------------
// Kernel 3: fused merge (8 bf16 partials) + output projection + residual.
// grid(64 s-tiles, 2 o-halves, 4 n) = 512 blocks, 256 thr.
// ---------------------------------------------------------------------------
__global__ __launch_bounds__(256, 4)
void outproj_kernel(const float* __restrict__ x,
                    const unsigned short* __restrict__ wbf,
                    const float* __restrict__ b_out,
                    const unsigned short* __restrict__ Opart,
                    const float* __restrict__ lbuf,
                    float* __restrict__ out) {
    const int tid  = threadIdx.x;
    const int wid  = tid >> 6;
    const int lane = tid & 63;
    const int quad = lane >> 4;
    const int l15  = lane & 15;
    const int oh = blockIdx.y;
    const int n  = blockIdx.z;
    const int sw = blockIdx.x * 64 + wid * 16;
    const int T  = NB * NS;

    const int srow = n * NS + sw + l15;
    float l = 0.f;
#pragma unroll
    for (int k = 0; k < SPLIT; k++) l += lbuf[k * T + srow];
    float rinv = 1.0f / l;

    bf16x8 yb[4];
#pragma unroll
    for (int kc = 0; kc < 4; kc++) {
        float f0 = 0.f, f1 = 0.f, f2 = 0.f, f3 = 0.f;
        float f4 = 0.f, f5 = 0.f, f6 = 0.f, f7 = 0.f;
#pragma unroll
        for (int k = 0; k < SPLIT; k++) {
            uint4 v = *(const uint4*)(Opart + ((size_t)k * T + srow) * CI + kc * 32 + quad * 8);
            f0 += bf2f(v.x & 0xffffu); f1 += bf2f(v.x >> 16);
            f2 += bf2f(v.y & 0xffffu); f3 += bf2f(v.y >> 16);
            f4 += bf2f(v.z & 0xffffu); f5 += bf2f(v.z >> 16);
            f6 += bf2f(v.w & 0xffffu); f7 += bf2f(v.w >> 16);
        }
        union { unsigned int uu[4]; bf16x8 vv; } r;
        r.uu[0] = pk2(f0 * rinv, f1 * rinv);
        r.uu[1] = pk2(f2 * rinv, f3 * rinv);
        r.uu[2] = pk2(f4 * rinv, f5 * rinv);
        r.uu[3] = pk2(f6 * rinv, f7 * rinv);
        yb[kc] = r.vv;
    }

    const unsigned short* wob = wbf + 3 * 32768 + (size_t)oh * 128 * CI;
    f32x4 acc[8];
#pragma unroll
    for (int ot = 0; ot < 8; ot++) acc[ot] = (f32x4){0.f, 0.f, 0.f, 0.f};
#pragma unroll
    for (int kc = 0; kc < 4; kc++) {
#pragma unroll
        for (int ot = 0; ot < 8; ot++) {
            bf16x8 wa = *(const bf16x8*)(wob + (size_t)(ot * 16 + l15) * CI + kc * 32 + quad * 8);
            acc[ot] = MFMA16(wa, yb[kc], acc[ot]);
        }
    }
#pragma unroll
    for (int ot = 0; ot < 8; ot++) {
#pragma unroll
        for (int r = 0; r < 4; r++) {
            int o = oh * 128 + ot * 16 + quad * 4 + r;
            size_t idx = ((size_t)n * CH + o) * NS + sw + l15;
            out[idx] = x[idx] + acc[ot][r] + b_out[o];
        }
    }
}

// ---------------------------------------------------------------------------
extern "C" void kernel_launch(void* const* d_in, const int* in_sizes, int n_in,
                              void* d_out, int out_size, void* d_ws, size_t ws_size,
                              hipStream_t stream) {
    const float* x     = (const float*)d_in[0];
    const float* w_g   = (const float*)d_in[1];
    const float* b_g   = (const float*)d_in[2];
    const float* w_th  = (const float*)d_in[3];
    const float* b_th  = (const float*)d_in[4];
    const float* w_ph  = (const float*)d_in[5];
    const float* b_ph  = (const float*)d_in[6];
    const float* w_out = (const float*)d_in[7];
    const float* b_out = (const float*)d_in[8];
    float* out = (float*)d_out;

    char* ws = (char*)d_ws;
    unsigned short* theta = (unsigned short*)(ws + 0);          //  4 MiB
    unsigned short* phi   = (unsigned short*)(ws + 4194304);    //  4 MiB
    unsigned short* gT    = (unsigned short*)(ws + 8388608);    //  4 MiB
    unsigned short* Opart = (unsigned short*)(ws + 12582912);   // 32 MiB (8 splits bf16)
    float* lbuf  = (float*)(ws + 46137344);                     // 512 KiB
    unsigned short* wbf = (unsigned short*)(ws + 46661632);     // 256 KiB
    float* bsc   = (float*)(ws + 46923776);                     //  1.5 KiB

    wcvt_kernel<<<512, 256, 0, stream>>>(w_g, w_th, w_ph, w_out, b_g, b_th, b_ph, wbf, bsc);
    proj_kernel<<<dim3(64, NB), 512, 0, stream>>>(x, wbf, bsc, theta, phi, gT);
    attn_kernel<<<dim3(32, 16), 256, 0, stream>>>(theta, phi, gT, Opart, lbuf);
    outproj_kernel<<<dim3(64, 2, NB), 256, 0, stream>>>(x, wbf, b_out, Opart, lbuf, out);
}

// Round 5
// 204.732 us; speedup vs baseline: 1.0250x; 1.0250x over previous
//
#include <hip/hip_runtime.h>
#include <cmath>

typedef __attribute__((ext_vector_type(8))) short bf16x8;
typedef __attribute__((ext_vector_type(4))) float f32x4;
typedef __attribute__((ext_vector_type(16))) float f32x16;

#define MFMA16(a,b,c)  __builtin_amdgcn_mfma_f32_16x16x32_bf16((a),(b),(c),0,0,0)
#define MFMA32(a,b,c)  __builtin_amdgcn_mfma_f32_32x32x16_bf16((a),(b),(c),0,0,0)

#if __has_builtin(__builtin_amdgcn_exp2f)
#define EXP2F(x) __builtin_amdgcn_exp2f(x)
#else
#define EXP2F(x) exp2f(x)
#endif

// sqrt(128) * log2(e): folded into w_theta/b_theta at wcvt time.
#define KSCALE 16.3222312f

#define NB 4
#define CH 256
#define CI 128
#define NS 4096   // 64*64 spatial

__device__ __forceinline__ unsigned short f2bf(float f) {
    unsigned int u = __builtin_bit_cast(unsigned int, f);
    u += 0x7fffu + ((u >> 16) & 1u);           // RNE
    return (unsigned short)(u >> 16);
}
__device__ __forceinline__ unsigned int pk2(float lo, float hi) {
    return (unsigned int)f2bf(lo) | ((unsigned int)f2bf(hi) << 16);
}
// truncating pack (softmax P only): 1-op v_perm_b32
__device__ __forceinline__ unsigned int pkt(float lo, float hi) {
    return __builtin_amdgcn_perm(__builtin_bit_cast(unsigned int, hi),
                                 __builtin_bit_cast(unsigned int, lo), 0x07060302u);
}
__device__ __forceinline__ float bf2f(unsigned int ush) {   // low 16 bits
    return __builtin_bit_cast(float, ush << 16);
}

// Half-exchange for P-fragment assembly (verified R3).
// Call as plswap(wLow, wHigh):
//   in : wLow  = even-g word, lane-half h holds s16 (4h+m0, 4h+m0+1)
//        wHigh = odd-g  word, lane-half h holds s16 (8+4h+m0, 8+4h+m0+1)
//   out: wLow  = fragment k-low word, wHigh = fragment k-high word
__device__ __forceinline__ void plswap(unsigned int& wLow, unsigned int& wHigh) {
    asm volatile("v_permlane32_swap_b32 %0, %1" : "+v"(wLow), "+v"(wHigh));
}

__device__ __forceinline__ f32x16 zero16() {
    f32x16 v;
#pragma unroll
    for (int i = 0; i < 16; i++) v[i] = 0.f;
    return v;
}

// async global->LDS 16B per lane: LDS dest = wave-uniform base + lane*16
__device__ __forceinline__ void gload16(void* lds, const void* g) {
    __builtin_amdgcn_global_load_lds(
        (const __attribute__((address_space(1))) unsigned int*)g,
        (__attribute__((address_space(3))) unsigned int*)lds,
        16, 0, 0);
}

// ---------------------------------------------------------------------------
// Kernel 0: one-time weight convert to bf16 (KSCALE folded into theta).
// ---------------------------------------------------------------------------
__global__ void wcvt_kernel(const float* __restrict__ w_g, const float* __restrict__ w_th,
                            const float* __restrict__ w_ph, const float* __restrict__ w_out,
                            const float* __restrict__ b_g, const float* __restrict__ b_th,
                            const float* __restrict__ b_ph,
                            unsigned short* __restrict__ wbf, float* __restrict__ bsc) {
    int i = blockIdx.x * 256 + threadIdx.x;     // 0..131071
    float v;
    if (i < 32768)        v = w_g[i];
    else if (i < 65536)   v = w_th[i - 32768] * KSCALE;
    else if (i < 98304)   v = w_ph[i - 65536];
    else                  v = w_out[i - 98304];
    wbf[i] = f2bf(v);
    if (i < 128)          bsc[i] = b_g[i];
    else if (i < 256)     bsc[i] = b_th[i - 128] * KSCALE;
    else if (i < 384)     bsc[i] = b_ph[i - 256];
}

// ---------------------------------------------------------------------------
// Kernel 1: FUSED projections — one x staging serves g/theta/phi (x read 1x).
// grid(64 s-tiles of 64, 4 n) = 256 blocks, 512 thr (8 waves).
// ---------------------------------------------------------------------------
__global__ __launch_bounds__(512, 2)
void proj_kernel(const float* __restrict__ x,
                 const unsigned short* __restrict__ wbf, const float* __restrict__ bsc,
                 unsigned short* __restrict__ theta,
                 unsigned short* __restrict__ phi,
                 unsigned short* __restrict__ gT) {
    const int tid  = threadIdx.x;
    const int wid  = tid >> 6;         // 0..7
    const int lane = tid & 63;
    const int quad = lane >> 4;
    const int l15  = lane & 15;
    const int stile = blockIdx.x;      // 0..63
    const int n     = blockIdx.y;
    const int s0    = stile * 64;

    const float* xN = x + (size_t)n * CH * NS;

    __shared__ unsigned int xp[64 * 128];   // 32 KB, swizzled

    // stage: 2048 tasks (128 c-pairs x 16 s-spans of float4), 4/thread
#pragma unroll
    for (int i = 0; i < 4; i++) {
        int t  = i * 512 + tid;
        int s4 = t & 15;
        int cp = t >> 4;                    // 0..127
        const float* p0 = xN + (size_t)(2 * cp) * NS + s0 + s4 * 4;
        float4 a = *(const float4*)p0;
        float4 b = *(const float4*)(p0 + NS);
        int col = (((cp >> 2) ^ (s4 & 7)) << 2) | (cp & 3);   // row>>2 == s4
        unsigned int* xr = xp + (s4 * 4) * 128 + col;
        xr[0]   = pk2(a.x, b.x);
        xr[128] = pk2(a.y, b.y);
        xr[256] = pk2(a.z, b.z);
        xr[384] = pk2(a.w, b.w);
    }
    __syncthreads();

    const int srow = (wid & 3) * 16 + l15;
    const int oh   = wid >> 2;              // o-half
    const int sw7  = (srow >> 2) & 7;
#pragma unroll
    for (int wi = 0; wi < 3; wi++) {
        f32x4 acc[4];
#pragma unroll
        for (int ot = 0; ot < 4; ot++) acc[ot] = (f32x4){0.f, 0.f, 0.f, 0.f};
        const unsigned short* W = wbf + (size_t)wi * 32768 + (size_t)oh * 64 * CH;
#pragma unroll
        for (int kc = 0; kc < 8; kc++) {
            bf16x8 af = *(const bf16x8*)(&xp[srow * 128 + (((kc * 4 + quad) ^ sw7) << 2)]);
#pragma unroll
            for (int ot = 0; ot < 4; ot++) {
                bf16x8 wf = *(const bf16x8*)(W + (size_t)(ot * 16 + l15) * CH + kc * 32 + quad * 8);
                acc[ot] = MFMA16(af, wf, acc[ot]);
            }
        }
        const float* Bv = bsc + wi * 128 + oh * 64;
#pragma unroll
        for (int ot = 0; ot < 4; ot++) {
            int o = oh * 64 + ot * 16 + l15;
            float bias = Bv[ot * 16 + l15];
#pragma unroll
            for (int r = 0; r < 4; r++) {
                int sg = s0 + (wid & 3) * 16 + quad * 4 + r;
                float v = acc[ot][r] + bias;
                if (wi == 0)
                    gT[((size_t)n * CI + o) * NS + sg] = f2bf(v);
                else if (wi == 1)
                    theta[((size_t)n * NS + sg) * CI + o] = f2bf(v);
                else
                    phi[((size_t)n * NS + sg) * CI + o] = f2bf(v);
            }
        }
    }
}

// ---------------------------------------------------------------------------
// Kernel 2: flash attention partials — R3 structure (q=32/wave, split=4,
// proven regs) with V READ DIRECTLY FROM GLOBAL (no V LDS staging/reads).
// gT's [c][s] layout makes the PV A-fragment a contiguous 16B/lane load:
// vf = gN[c*NS + s0 + ks*16 + lh32*8].  LDS read traffic halves (R3 model:
// LDS pipe ~20us/CU dominant); V bytes move to the VMEM/L2 path which
// overlaps.  All 32 qb-blocks of an sn land on the same XCD ((x+16y)%8 =
// sn%8) -> V slice is L2-local.  LDS now 32 KB (K dbuf only; epilogue tb
// overlays it).  grid(16 = split*4+n, 32 qb) = 512 blocks, 256 thr.
// ---------------------------------------------------------------------------
__global__ __launch_bounds__(256, 2)
void attn_kernel(const unsigned short* __restrict__ theta,
                 const unsigned short* __restrict__ phi,
                 const unsigned short* __restrict__ gT,
                 unsigned short* __restrict__ Opart,
                 float* __restrict__ lbuf) {
    const int tid  = threadIdx.x;
    const int wid  = tid >> 6;          // 0..3
    const int lane = tid & 63;
    const int l31  = lane & 31;
    const int lh32 = lane >> 5;         // 0..1
    const int sn    = blockIdx.x;       // 0..15
    const int split = sn >> 2;          // 0..3
    const int n     = sn & 3;
    const int qb    = blockIdx.y;       // 0..31
    const int qbase = qb * 128 + wid * 32;

    const unsigned short* thN = theta + (size_t)n * NS * CI;
    const unsigned short* phN = phi   + (size_t)n * NS * CI;
    const unsigned short* gN  = gT    + (size_t)n * CI * NS;

    // K dbuf: 2 x [64 s][128 c] (slot ^ (s&15))   32 KB  (epilogue tb overlays)
    __shared__ unsigned short smem[16384];
    unsigned short* Kb = smem;              // + cur*8192

    // Q B-fragments: col = q = l31, k = lh32*8 + e within each 16-c slice
    bf16x8 qf[8];
#pragma unroll
    for (int kc = 0; kc < 8; kc++)
        qf[kc] = *(const bf16x8*)(thN + (size_t)(qbase + l31) * CI + kc * 16 + lh32 * 8);

    f32x16 O[4];    // O^T tiles: row c = ct*32 + (reg&3)+8*(reg>>2)+4*lh32, col q = l31
#pragma unroll
    for (int ct = 0; ct < 4; ct++) O[ct] = zero16();
    float lrun = 0.f;

    const int sbase0 = split * 1024;
    const int lh16 = lane >> 4, lm16 = lane & 15;

    // stage K chunk 0 -> buffer 0 (4 segs per wave)
#pragma unroll
    for (int i = 0; i < 4; i++) {
        int seg = wid * 4 + i;                  // 0..15
        int s   = seg * 4 + lh16;               // 0..63
        int j   = lm16 ^ (s & 15);
        gload16(Kb + seg * 512, phN + (size_t)(sbase0 + s) * CI + j * 8);
    }

    // V base pointers per ct (advance 64 s per chunk)
    const unsigned short* vp[4];
#pragma unroll
    for (int ct = 0; ct < 4; ct++)
        vp[ct] = gN + (size_t)(ct * 32 + l31) * NS + sbase0 + lh32 * 8;

    for (int ck = 0; ck < 16; ck++) {
        const int cur = ck & 1, nxt = cur ^ 1;
        unsigned short* Kc = Kb + cur * 8192;
        __syncthreads();    // drains cur K loads; prev compute done

        if (ck + 1 < 16) {  // async prefetch next K chunk
            const int sb1 = sbase0 + (ck + 1) * 64;
#pragma unroll
            for (int i = 0; i < 4; i++) {
                int seg = wid * 4 + i;
                int s   = seg * 4 + lh16;
                int j   = lm16 ^ (s & 15);
                gload16(Kb + nxt * 8192 + seg * 512, phN + (size_t)(sb1 + s) * CI + j * 8);
            }
        }

        // QK^T -> S^T: 2 s-blocks x 8 c-slices
        f32x16 S[2];
        S[0] = zero16(); S[1] = zero16();
        __builtin_amdgcn_s_setprio(1);
#pragma unroll
        for (int sb = 0; sb < 2; sb++) {
#pragma unroll
            for (int kc = 0; kc < 8; kc++) {
                int s = sb * 32 + l31;
                bf16x8 kf = *(const bf16x8*)(Kc + s * 128 + (((kc * 2 + lh32) ^ (s & 15)) * 8));
                S[sb] = MFMA32(kf, qf[kc], S[sb]);
            }
        }
        __builtin_amdgcn_s_setprio(0);

        // softmax: p = exp2(S); assemble P B-fragments (k=s) per 16-s slice.
        bf16x8 pf[4];
        float lsum = 0.f;
#pragma unroll
        for (int ks = 0; ks < 4; ks++) {
            const int sb = ks >> 1, b = ks & 1;
            float pA[4], pB[4];
#pragma unroll
            for (int m = 0; m < 4; m++) {
                pA[m] = EXP2F(S[sb][(2 * b) * 4 + m]);       // even g: s16 = m+4h
                pB[m] = EXP2F(S[sb][(2 * b + 1) * 4 + m]);   // odd g:  s16 = 8+m+4h
            }
            lsum += ((pA[0] + pA[1]) + (pA[2] + pA[3]))
                  + ((pB[0] + pB[1]) + (pB[2] + pB[3]));
            unsigned int wA0 = pkt(pA[0], pA[1]);
            unsigned int wA1 = pkt(pA[2], pA[3]);
            unsigned int wB0 = pkt(pB[0], pB[1]);
            unsigned int wB1 = pkt(pB[2], pB[3]);
            plswap(wA0, wB0);   // wA0 -> u0, wB0 -> u2
            plswap(wA1, wB1);   // wA1 -> u1, wB1 -> u3
            union { unsigned int u[4]; bf16x8 v; } P;
            P.u[0] = wA0; P.u[1] = wA1; P.u[2] = wB0; P.u[3] = wB1;
            pf[ks] = P.v;
        }
        lrun += lsum;

        // PV: O^T += V^T . P^T over 4 K=16 slices; V direct from global (L2).
        __builtin_amdgcn_s_setprio(1);
#pragma unroll
        for (int ks = 0; ks < 4; ks++) {
#pragma unroll
            for (int ct = 0; ct < 4; ct++) {
                bf16x8 vf = *(const bf16x8*)(vp[ct] + ks * 16);
                O[ct] = MFMA32(vf, pf[ks], O[ct]);
            }
        }
        __builtin_amdgcn_s_setprio(0);
#pragma unroll
        for (int ct = 0; ct < 4; ct++) vp[ct] += 64;   // next chunk
    }

    // epilogue: O^T (32x32 tiles) -> Opart[q][c] bf16 via per-wave LDS
    // transpose, 2 passes of 2 ct (8 KB tb per wave), XOR-swizzled 16B slots.
    __syncthreads();
    float* tb = (float*)smem + wid * 2048;   // 4 waves x 8 KB = 32 KB
    const size_t obase = ((size_t)(split * NB + n)) * NS * CI;
#pragma unroll
    for (int pass = 0; pass < 2; pass++) {
#pragma unroll
        for (int cti = 0; cti < 2; cti++) {
            const int ct = pass * 2 + cti;
#pragma unroll
            for (int g = 0; g < 4; g++) {
                const int c_local = cti * 32 + 8 * g + 4 * lh32;   // +0..3
                const int slot = (c_local >> 2) ^ (l31 & 15);
                f32x4 v;
                v[0] = O[ct][4 * g + 0]; v[1] = O[ct][4 * g + 1];
                v[2] = O[ct][4 * g + 2]; v[3] = O[ct][4 * g + 3];
                *(f32x4*)(tb + l31 * 64 + slot * 4) = v;
            }
        }
#pragma unroll
        for (int i = 0; i < 8; i++) {
            const int qr  = i * 4 + (lane >> 4);    // 0..31
            const int lin = lane & 15;
            f32x4 v = *(const f32x4*)(tb + qr * 64 + ((lin ^ (qr & 15)) * 4));
            uint2 w;
            w.x = pk2(v[0], v[1]);
            w.y = pk2(v[2], v[3]);
            *(uint2*)(Opart + obase + (size_t)(qbase + qr) * CI + pass * 64 + lin * 4) = w;
        }
        __syncthreads();   // tb region reused across passes
    }
    lrun += __shfl_xor(lrun, 32);
    if (lane < 32)
        lbuf[(split * NB + n) * NS + qbase + l31] = lrun;
}

// ---------------------------------------------------------------------------
// Kernel 3: fused merge (4 bf16 partials) + output projection + residual.
// grid(64 s-tiles, 2 o-halves, 4 n) = 512 blocks, 256 thr.
// ---------------------------------------------------------------------------
__global__ __launch_bounds__(256, 4)
void outproj_kernel(const float* __restrict__ x,
                    const unsigned short* __restrict__ wbf,
                    const float* __restrict__ b_out,
                    const unsigned short* __restrict__ Opart,
                    const float* __restrict__ lbuf,
                    float* __restrict__ out) {
    const int tid  = threadIdx.x;
    const int wid  = tid >> 6;
    const int lane = tid & 63;
    const int quad = lane >> 4;
    const int l15  = lane & 15;
    const int oh = blockIdx.y;
    const int n  = blockIdx.z;
    const int sw = blockIdx.x * 64 + wid * 16;
    const int T  = NB * NS;

    const int srow = n * NS + sw + l15;
    float l = 0.f;
#pragma unroll
    for (int k = 0; k < 4; k++) l += lbuf[k * T + srow];
    float rinv = 1.0f / l;

    bf16x8 yb[4];
#pragma unroll
    for (int kc = 0; kc < 4; kc++) {
        float f0 = 0.f, f1 = 0.f, f2 = 0.f, f3 = 0.f;
        float f4 = 0.f, f5 = 0.f, f6 = 0.f, f7 = 0.f;
#pragma unroll
        for (int k = 0; k < 4; k++) {
            uint4 v = *(const uint4*)(Opart + ((size_t)k * T + srow) * CI + kc * 32 + quad * 8);
            f0 += bf2f(v.x & 0xffffu); f1 += bf2f(v.x >> 16);
            f2 += bf2f(v.y & 0xffffu); f3 += bf2f(v.y >> 16);
            f4 += bf2f(v.z & 0xffffu); f5 += bf2f(v.z >> 16);
            f6 += bf2f(v.w & 0xffffu); f7 += bf2f(v.w >> 16);
        }
        union { unsigned int uu[4]; bf16x8 vv; } r;
        r.uu[0] = pk2(f0 * rinv, f1 * rinv);
        r.uu[1] = pk2(f2 * rinv, f3 * rinv);
        r.uu[2] = pk2(f4 * rinv, f5 * rinv);
        r.uu[3] = pk2(f6 * rinv, f7 * rinv);
        yb[kc] = r.vv;
    }

    const unsigned short* wob = wbf + 3 * 32768 + (size_t)oh * 128 * CI;
    f32x4 acc[8];
#pragma unroll
    for (int ot = 0; ot < 8; ot++) acc[ot] = (f32x4){0.f, 0.f, 0.f, 0.f};
#pragma unroll
    for (int kc = 0; kc < 4; kc++) {
#pragma unroll
        for (int ot = 0; ot < 8; ot++) {
            bf16x8 wa = *(const bf16x8*)(wob + (size_t)(ot * 16 + l15) * CI + kc * 32 + quad * 8);
            acc[ot] = MFMA16(wa, yb[kc], acc[ot]);
        }
    }
#pragma unroll
    for (int ot = 0; ot < 8; ot++) {
#pragma unroll
        for (int r = 0; r < 4; r++) {
            int o = oh * 128 + ot * 16 + quad * 4 + r;
            size_t idx = ((size_t)n * CH + o) * NS + sw + l15;
            out[idx] = x[idx] + acc[ot][r] + b_out[o];
        }
    }
}

// ---------------------------------------------------------------------------
extern "C" void kernel_launch(void* const* d_in, const int* in_sizes, int n_in,
                              void* d_out, int out_size, void* d_ws, size_t ws_size,
                              hipStream_t stream) {
    const float* x     = (const float*)d_in[0];
    const float* w_g   = (const float*)d_in[1];
    const float* b_g   = (const float*)d_in[2];
    const float* w_th  = (const float*)d_in[3];
    const float* b_th  = (const float*)d_in[4];
    const float* w_ph  = (const float*)d_in[5];
    const float* b_ph  = (const float*)d_in[6];
    const float* w_out = (const float*)d_in[7];
    const float* b_out = (const float*)d_in[8];
    float* out = (float*)d_out;

    char* ws = (char*)d_ws;
    unsigned short* theta = (unsigned short*)(ws + 0);          //  4 MiB
    unsigned short* phi   = (unsigned short*)(ws + 4194304);    //  4 MiB
    unsigned short* gT    = (unsigned short*)(ws + 8388608);    //  4 MiB
    unsigned short* Opart = (unsigned short*)(ws + 12582912);   // 16 MiB (4 splits bf16)
    float* lbuf  = (float*)(ws + 29360128);                     // 256 KiB
    unsigned short* wbf = (unsigned short*)(ws + 29622272);     // 256 KiB
    float* bsc   = (float*)(ws + 29884416);                     //  1.5 KiB

    wcvt_kernel<<<512, 256, 0, stream>>>(w_g, w_th, w_ph, w_out, b_g, b_th, b_ph, wbf, bsc);
    proj_kernel<<<dim3(64, NB), 512, 0, stream>>>(x, wbf, bsc, theta, phi, gT);
    attn_kernel<<<dim3(16, 32), 256, 0, stream>>>(theta, phi, gT, Opart, lbuf);
    outproj_kernel<<<dim3(64, 2, NB), 256, 0, stream>>>(x, wbf, b_out, Opart, lbuf, out);
}

// Round 6
// 195.510 us; speedup vs baseline: 1.0734x; 1.0472x over previous
//
#include <hip/hip_runtime.h>
#include <cmath>

typedef __attribute__((ext_vector_type(8))) short bf16x8;
typedef __attribute__((ext_vector_type(4))) float f32x4;
typedef __attribute__((ext_vector_type(16))) float f32x16;

#define MFMA16(a,b,c)  __builtin_amdgcn_mfma_f32_16x16x32_bf16((a),(b),(c),0,0,0)
#define MFMA32(a,b,c)  __builtin_amdgcn_mfma_f32_32x32x16_bf16((a),(b),(c),0,0,0)

#if __has_builtin(__builtin_amdgcn_exp2f)
#define EXP2F(x) __builtin_amdgcn_exp2f(x)
#else
#define EXP2F(x) exp2f(x)
#endif

// sqrt(128) * log2(e): folded into w_theta/b_theta at wcvt time.
#define KSCALE 16.3222312f

#define NB 4
#define CH 256
#define CI 128
#define NS 4096   // 64*64 spatial

__device__ __forceinline__ unsigned short f2bf(float f) {
    unsigned int u = __builtin_bit_cast(unsigned int, f);
    u += 0x7fffu + ((u >> 16) & 1u);           // RNE
    return (unsigned short)(u >> 16);
}
__device__ __forceinline__ unsigned int pk2(float lo, float hi) {
    return (unsigned int)f2bf(lo) | ((unsigned int)f2bf(hi) << 16);
}
// truncating pack (softmax P only): 1-op v_perm_b32
__device__ __forceinline__ unsigned int pkt(float lo, float hi) {
    return __builtin_amdgcn_perm(__builtin_bit_cast(unsigned int, hi),
                                 __builtin_bit_cast(unsigned int, lo), 0x07060302u);
}
__device__ __forceinline__ float bf2f(unsigned int ush) {   // low 16 bits
    return __builtin_bit_cast(float, ush << 16);
}

// Half-exchange for P-fragment assembly (verified R3).
// Call as plswap(wLow, wHigh):
//   in : wLow  = even-g word, lane-half h holds s16 (4h+m0, 4h+m0+1)
//        wHigh = odd-g  word, lane-half h holds s16 (8+4h+m0, 8+4h+m0+1)
//   out: wLow  = fragment k-low word, wHigh = fragment k-high word
__device__ __forceinline__ void plswap(unsigned int& wLow, unsigned int& wHigh) {
    asm volatile("v_permlane32_swap_b32 %0, %1" : "+v"(wLow), "+v"(wHigh));
}

__device__ __forceinline__ f32x16 zero16() {
    f32x16 v;
#pragma unroll
    for (int i = 0; i < 16; i++) v[i] = 0.f;
    return v;
}

// async global->LDS 16B per lane: LDS dest = wave-uniform base + lane*16
__device__ __forceinline__ void gload16(void* lds, const void* g) {
    __builtin_amdgcn_global_load_lds(
        (const __attribute__((address_space(1))) unsigned int*)g,
        (__attribute__((address_space(3))) unsigned int*)lds,
        16, 0, 0);
}

// ---------------------------------------------------------------------------
// Kernel 0: one-time weight convert to bf16 (KSCALE folded into theta).
// ---------------------------------------------------------------------------
__global__ void wcvt_kernel(const float* __restrict__ w_g, const float* __restrict__ w_th,
                            const float* __restrict__ w_ph, const float* __restrict__ w_out,
                            const float* __restrict__ b_g, const float* __restrict__ b_th,
                            const float* __restrict__ b_ph,
                            unsigned short* __restrict__ wbf, float* __restrict__ bsc) {
    int i = blockIdx.x * 256 + threadIdx.x;     // 0..131071
    float v;
    if (i < 32768)        v = w_g[i];
    else if (i < 65536)   v = w_th[i - 32768] * KSCALE;
    else if (i < 98304)   v = w_ph[i - 65536];
    else                  v = w_out[i - 98304];
    wbf[i] = f2bf(v);
    if (i < 128)          bsc[i] = b_g[i];
    else if (i < 256)     bsc[i] = b_th[i - 128] * KSCALE;
    else if (i < 384)     bsc[i] = b_ph[i - 256];
}

// ---------------------------------------------------------------------------
// Kernel 1: FUSED projections — one x staging serves g/theta/phi (x read 1x).
// grid(64 s-tiles of 64, 4 n) = 256 blocks, 512 thr (8 waves).
// ---------------------------------------------------------------------------
__global__ __launch_bounds__(512, 2)
void proj_kernel(const float* __restrict__ x,
                 const unsigned short* __restrict__ wbf, const float* __restrict__ bsc,
                 unsigned short* __restrict__ theta,
                 unsigned short* __restrict__ phi,
                 unsigned short* __restrict__ gT) {
    const int tid  = threadIdx.x;
    const int wid  = tid >> 6;         // 0..7
    const int lane = tid & 63;
    const int quad = lane >> 4;
    const int l15  = lane & 15;
    const int stile = blockIdx.x;      // 0..63
    const int n     = blockIdx.y;
    const int s0    = stile * 64;

    const float* xN = x + (size_t)n * CH * NS;

    __shared__ unsigned int xp[64 * 128];   // 32 KB, swizzled

    // stage: 2048 tasks (128 c-pairs x 16 s-spans of float4), 4/thread
#pragma unroll
    for (int i = 0; i < 4; i++) {
        int t  = i * 512 + tid;
        int s4 = t & 15;
        int cp = t >> 4;                    // 0..127
        const float* p0 = xN + (size_t)(2 * cp) * NS + s0 + s4 * 4;
        float4 a = *(const float4*)p0;
        float4 b = *(const float4*)(p0 + NS);
        int col = (((cp >> 2) ^ (s4 & 7)) << 2) | (cp & 3);   // row>>2 == s4
        unsigned int* xr = xp + (s4 * 4) * 128 + col;
        xr[0]   = pk2(a.x, b.x);
        xr[128] = pk2(a.y, b.y);
        xr[256] = pk2(a.z, b.z);
        xr[384] = pk2(a.w, b.w);
    }
    __syncthreads();

    const int srow = (wid & 3) * 16 + l15;
    const int oh   = wid >> 2;              // o-half
    const int sw7  = (srow >> 2) & 7;
#pragma unroll
    for (int wi = 0; wi < 3; wi++) {
        f32x4 acc[4];
#pragma unroll
        for (int ot = 0; ot < 4; ot++) acc[ot] = (f32x4){0.f, 0.f, 0.f, 0.f};
        const unsigned short* W = wbf + (size_t)wi * 32768 + (size_t)oh * 64 * CH;
#pragma unroll
        for (int kc = 0; kc < 8; kc++) {
            bf16x8 af = *(const bf16x8*)(&xp[srow * 128 + (((kc * 4 + quad) ^ sw7) << 2)]);
#pragma unroll
            for (int ot = 0; ot < 4; ot++) {
                bf16x8 wf = *(const bf16x8*)(W + (size_t)(ot * 16 + l15) * CH + kc * 32 + quad * 8);
                acc[ot] = MFMA16(af, wf, acc[ot]);
            }
        }
        const float* Bv = bsc + wi * 128 + oh * 64;
#pragma unroll
        for (int ot = 0; ot < 4; ot++) {
            int o = oh * 64 + ot * 16 + l15;
            float bias = Bv[ot * 16 + l15];
#pragma unroll
            for (int r = 0; r < 4; r++) {
                int sg = s0 + (wid & 3) * 16 + quad * 4 + r;
                float v = acc[ot][r] + bias;
                if (wi == 0)
                    gT[((size_t)n * CI + o) * NS + sg] = f2bf(v);
                else if (wi == 1)
                    theta[((size_t)n * NS + sg) * CI + o] = f2bf(v);
                else
                    phi[((size_t)n * NS + sg) * CI + o] = f2bf(v);
            }
        }
    }
}

// ---------------------------------------------------------------------------
// Kernel 2: flash attention partials — R5 structure (V direct from global,
// K-only LDS, 32 KB) + T14 FIX: all 16 V fragment loads for the CURRENT
// chunk are issued at chunk top (right after the barrier, before QK^T),
// pinned with sched_barrier(0) so the scheduler cannot sink them.  They are
// consumed ~2000 cycles later in PV — L2 latency fully hidden (R5 had them
// inline in PV -> latency-serialized, 87us).  QK^T S0/S1 chains interleaved.
// Regs: O 64 AGPR + qf 32 + S 32 + vf 64 + misc ~ 230 unified < 256.
// grid(16 = split*4+n, 32 qb) = 512 blocks, 256 thr.
// ---------------------------------------------------------------------------
__global__ __launch_bounds__(256, 2)
void attn_kernel(const unsigned short* __restrict__ theta,
                 const unsigned short* __restrict__ phi,
                 const unsigned short* __restrict__ gT,
                 unsigned short* __restrict__ Opart,
                 float* __restrict__ lbuf) {
    const int tid  = threadIdx.x;
    const int wid  = tid >> 6;          // 0..3
    const int lane = tid & 63;
    const int l31  = lane & 31;
    const int lh32 = lane >> 5;         // 0..1
    const int sn    = blockIdx.x;       // 0..15
    const int split = sn >> 2;          // 0..3
    const int n     = sn & 3;
    const int qb    = blockIdx.y;       // 0..31
    const int qbase = qb * 128 + wid * 32;

    const unsigned short* thN = theta + (size_t)n * NS * CI;
    const unsigned short* phN = phi   + (size_t)n * NS * CI;
    const unsigned short* gN  = gT    + (size_t)n * CI * NS;

    // K dbuf: 2 x [64 s][128 c] (slot ^ (s&15))   32 KB  (epilogue tb overlays)
    __shared__ unsigned short smem[16384];
    unsigned short* Kb = smem;              // + cur*8192

    // Q B-fragments: col = q = l31, k = lh32*8 + e within each 16-c slice
    bf16x8 qf[8];
#pragma unroll
    for (int kc = 0; kc < 8; kc++)
        qf[kc] = *(const bf16x8*)(thN + (size_t)(qbase + l31) * CI + kc * 16 + lh32 * 8);

    f32x16 O[4];    // O^T tiles: row c = ct*32 + (reg&3)+8*(reg>>2)+4*lh32, col q = l31
#pragma unroll
    for (int ct = 0; ct < 4; ct++) O[ct] = zero16();
    float lrun = 0.f;

    const int sbase0 = split * 1024;
    const int lh16 = lane >> 4, lm16 = lane & 15;

    // stage K chunk 0 -> buffer 0 (4 segs per wave)
#pragma unroll
    for (int i = 0; i < 4; i++) {
        int seg = wid * 4 + i;                  // 0..15
        int s   = seg * 4 + lh16;               // 0..63
        int j   = lm16 ^ (s & 15);
        gload16(Kb + seg * 512, phN + (size_t)(sbase0 + s) * CI + j * 8);
    }

    // V base pointers per ct (advance 64 s per chunk)
    const unsigned short* vp[4];
#pragma unroll
    for (int ct = 0; ct < 4; ct++)
        vp[ct] = gN + (size_t)(ct * 32 + l31) * NS + sbase0 + lh32 * 8;

    for (int ck = 0; ck < 16; ck++) {
        const int cur = ck & 1, nxt = cur ^ 1;
        unsigned short* Kc = Kb + cur * 8192;
        __syncthreads();    // drains cur K loads; prev compute done

        // ---- T14 issue-early: all 16 V fragments for THIS chunk ----
        bf16x8 vf[16];
#pragma unroll
        for (int ks = 0; ks < 4; ks++)
#pragma unroll
            for (int ct = 0; ct < 4; ct++)
                vf[ks * 4 + ct] = *(const bf16x8*)(vp[ct] + ks * 16);

        if (ck + 1 < 16) {  // async prefetch next K chunk
            const int sb1 = sbase0 + (ck + 1) * 64;
#pragma unroll
            for (int i = 0; i < 4; i++) {
                int seg = wid * 4 + i;
                int s   = seg * 4 + lh16;
                int j   = lm16 ^ (s & 15);
                gload16(Kb + nxt * 8192 + seg * 512, phN + (size_t)(sb1 + s) * CI + j * 8);
            }
        }
        // pin: nothing below may be hoisted above, loads may not sink below
        __builtin_amdgcn_sched_barrier(0);

        // QK^T -> S^T: interleaved S0/S1 chains, 8 c-slices
        f32x16 S0 = zero16(), S1 = zero16();
        __builtin_amdgcn_s_setprio(1);
#pragma unroll
        for (int kc = 0; kc < 8; kc++) {
            int s0r = l31;
            int s1r = 32 + l31;
            bf16x8 kf0 = *(const bf16x8*)(Kc + s0r * 128 + (((kc * 2 + lh32) ^ (s0r & 15)) * 8));
            bf16x8 kf1 = *(const bf16x8*)(Kc + s1r * 128 + (((kc * 2 + lh32) ^ (s1r & 15)) * 8));
            S0 = MFMA32(kf0, qf[kc], S0);
            S1 = MFMA32(kf1, qf[kc], S1);
        }
        __builtin_amdgcn_s_setprio(0);

        // softmax: p = exp2(S); assemble P B-fragments (k=s) per 16-s slice.
        bf16x8 pf[4];
        float lsum = 0.f;
#pragma unroll
        for (int ks = 0; ks < 4; ks++) {
            const f32x16& S = (ks < 2) ? S0 : S1;
            const int b = ks & 1;
            float pA[4], pB[4];
#pragma unroll
            for (int m = 0; m < 4; m++) {
                pA[m] = EXP2F(S[(2 * b) * 4 + m]);       // even g: s16 = m+4h
                pB[m] = EXP2F(S[(2 * b + 1) * 4 + m]);   // odd g:  s16 = 8+m+4h
            }
            lsum += ((pA[0] + pA[1]) + (pA[2] + pA[3]))
                  + ((pB[0] + pB[1]) + (pB[2] + pB[3]));
            unsigned int wA0 = pkt(pA[0], pA[1]);
            unsigned int wA1 = pkt(pA[2], pA[3]);
            unsigned int wB0 = pkt(pB[0], pB[1]);
            unsigned int wB1 = pkt(pB[2], pB[3]);
            plswap(wA0, wB0);   // wA0 -> u0, wB0 -> u2
            plswap(wA1, wB1);   // wA1 -> u1, wB1 -> u3
            union { unsigned int u[4]; bf16x8 v; } P;
            P.u[0] = wA0; P.u[1] = wA1; P.u[2] = wB0; P.u[3] = wB1;
            pf[ks] = P.v;
        }
        lrun += lsum;

        // PV: O^T += V^T . P^T over 4 K=16 slices; V already in registers.
        __builtin_amdgcn_s_setprio(1);
#pragma unroll
        for (int ks = 0; ks < 4; ks++) {
#pragma unroll
            for (int ct = 0; ct < 4; ct++) {
                O[ct] = MFMA32(vf[ks * 4 + ct], pf[ks], O[ct]);
            }
        }
        __builtin_amdgcn_s_setprio(0);
#pragma unroll
        for (int ct = 0; ct < 4; ct++) vp[ct] += 64;   // next chunk
    }

    // epilogue: O^T (32x32 tiles) -> Opart[q][c] bf16 via per-wave LDS
    // transpose, 2 passes of 2 ct (8 KB tb per wave), XOR-swizzled 16B slots.
    __syncthreads();
    float* tb = (float*)smem + wid * 2048;   // 4 waves x 8 KB = 32 KB
    const size_t obase = ((size_t)(split * NB + n)) * NS * CI;
#pragma unroll
    for (int pass = 0; pass < 2; pass++) {
#pragma unroll
        for (int cti = 0; cti < 2; cti++) {
            const int ct = pass * 2 + cti;
#pragma unroll
            for (int g = 0; g < 4; g++) {
                const int c_local = cti * 32 + 8 * g + 4 * lh32;   // +0..3
                const int slot = (c_local >> 2) ^ (l31 & 15);
                f32x4 v;
                v[0] = O[ct][4 * g + 0]; v[1] = O[ct][4 * g + 1];
                v[2] = O[ct][4 * g + 2]; v[3] = O[ct][4 * g + 3];
                *(f32x4*)(tb + l31 * 64 + slot * 4) = v;
            }
        }
#pragma unroll
        for (int i = 0; i < 8; i++) {
            const int qr  = i * 4 + (lane >> 4);    // 0..31
            const int lin = lane & 15;
            f32x4 v = *(const f32x4*)(tb + qr * 64 + ((lin ^ (qr & 15)) * 4));
            uint2 w;
            w.x = pk2(v[0], v[1]);
            w.y = pk2(v[2], v[3]);
            *(uint2*)(Opart + obase + (size_t)(qbase + qr) * CI + pass * 64 + lin * 4) = w;
        }
        __syncthreads();   // tb region reused across passes
    }
    lrun += __shfl_xor(lrun, 32);
    if (lane < 32)
        lbuf[(split * NB + n) * NS + qbase + l31] = lrun;
}

// ---------------------------------------------------------------------------
// Kernel 3: fused merge (4 bf16 partials) + output projection + residual.
// grid(64 s-tiles, 2 o-halves, 4 n) = 512 blocks, 256 thr.
// ---------------------------------------------------------------------------
__global__ __launch_bounds__(256, 4)
void outproj_kernel(const float* __restrict__ x,
                    const unsigned short* __restrict__ wbf,
                    const float* __restrict__ b_out,
                    const unsigned short* __restrict__ Opart,
                    const float* __restrict__ lbuf,
                    float* __restrict__ out) {
    const int tid  = threadIdx.x;
    const int wid  = tid >> 6;
    const int lane = tid & 63;
    const int quad = lane >> 4;
    const int l15  = lane & 15;
    const int oh = blockIdx.y;
    const int n  = blockIdx.z;
    const int sw = blockIdx.x * 64 + wid * 16;
    const int T  = NB * NS;

    const int srow = n * NS + sw + l15;
    float l = 0.f;
#pragma unroll
    for (int k = 0; k < 4; k++) l += lbuf[k * T + srow];
    float rinv = 1.0f / l;

    bf16x8 yb[4];
#pragma unroll
    for (int kc = 0; kc < 4; kc++) {
        float f0 = 0.f, f1 = 0.f, f2 = 0.f, f3 = 0.f;
        float f4 = 0.f, f5 = 0.f, f6 = 0.f, f7 = 0.f;
#pragma unroll
        for (int k = 0; k < 4; k++) {
            uint4 v = *(const uint4*)(Opart + ((size_t)k * T + srow) * CI + kc * 32 + quad * 8);
            f0 += bf2f(v.x & 0xffffu); f1 += bf2f(v.x >> 16);
            f2 += bf2f(v.y & 0xffffu); f3 += bf2f(v.y >> 16);
            f4 += bf2f(v.z & 0xffffu); f5 += bf2f(v.z >> 16);
            f6 += bf2f(v.w & 0xffffu); f7 += bf2f(v.w >> 16);
        }
        union { unsigned int uu[4]; bf16x8 vv; } r;
        r.uu[0] = pk2(f0 * rinv, f1 * rinv);
        r.uu[1] = pk2(f2 * rinv, f3 * rinv);
        r.uu[2] = pk2(f4 * rinv, f5 * rinv);
        r.uu[3] = pk2(f6 * rinv, f7 * rinv);
        yb[kc] = r.vv;
    }

    const unsigned short* wob = wbf + 3 * 32768 + (size_t)oh * 128 * CI;
    f32x4 acc[8];
#pragma unroll
    for (int ot = 0; ot < 8; ot++) acc[ot] = (f32x4){0.f, 0.f, 0.f, 0.f};
#pragma unroll
    for (int kc = 0; kc < 4; kc++) {
#pragma unroll
        for (int ot = 0; ot < 8; ot++) {
            bf16x8 wa = *(const bf16x8*)(wob + (size_t)(ot * 16 + l15) * CI + kc * 32 + quad * 8);
            acc[ot] = MFMA16(wa, yb[kc], acc[ot]);
        }
    }
#pragma unroll
    for (int ot = 0; ot < 8; ot++) {
#pragma unroll
        for (int r = 0; r < 4; r++) {
            int o = oh * 128 + ot * 16 + quad * 4 + r;
            size_t idx = ((size_t)n * CH + o) * NS + sw + l15;
            out[idx] = x[idx] + acc[ot][r] + b_out[o];
        }
    }
}

// ---------------------------------------------------------------------------
extern "C" void kernel_launch(void* const* d_in, const int* in_sizes, int n_in,
                              void* d_out, int out_size, void* d_ws, size_t ws_size,
                              hipStream_t stream) {
    const float* x     = (const float*)d_in[0];
    const float* w_g   = (const float*)d_in[1];
    const float* b_g   = (const float*)d_in[2];
    const float* w_th  = (const float*)d_in[3];
    const float* b_th  = (const float*)d_in[4];
    const float* w_ph  = (const float*)d_in[5];
    const float* b_ph  = (const float*)d_in[6];
    const float* w_out = (const float*)d_in[7];
    const float* b_out = (const float*)d_in[8];
    float* out = (float*)d_out;

    char* ws = (char*)d_ws;
    unsigned short* theta = (unsigned short*)(ws + 0);          //  4 MiB
    unsigned short* phi   = (unsigned short*)(ws + 4194304);    //  4 MiB
    unsigned short* gT    = (unsigned short*)(ws + 8388608);    //  4 MiB
    unsigned short* Opart = (unsigned short*)(ws + 12582912);   // 16 MiB (4 splits bf16)
    float* lbuf  = (float*)(ws + 29360128);                     // 256 KiB
    unsigned short* wbf = (unsigned short*)(ws + 29622272);     // 256 KiB
    float* bsc   = (float*)(ws + 29884416);                     //  1.5 KiB

    wcvt_kernel<<<512, 256, 0, stream>>>(w_g, w_th, w_ph, w_out, b_g, b_th, b_ph, wbf, bsc);
    proj_kernel<<<dim3(64, NB), 512, 0, stream>>>(x, wbf, bsc, theta, phi, gT);
    attn_kernel<<<dim3(16, 32), 256, 0, stream>>>(theta, phi, gT, Opart, lbuf);
    outproj_kernel<<<dim3(64, 2, NB), 256, 0, stream>>>(x, wbf, b_out, Opart, lbuf, out);
}

// Round 7
// 194.567 us; speedup vs baseline: 1.0786x; 1.0048x over previous
//
#include <hip/hip_runtime.h>
#include <cmath>

typedef __attribute__((ext_vector_type(8))) short bf16x8;
typedef __attribute__((ext_vector_type(4))) float f32x4;
typedef __attribute__((ext_vector_type(16))) float f32x16;

#define MFMA16(a,b,c)  __builtin_amdgcn_mfma_f32_16x16x32_bf16((a),(b),(c),0,0,0)
#define MFMA32(a,b,c)  __builtin_amdgcn_mfma_f32_32x32x16_bf16((a),(b),(c),0,0,0)

#if __has_builtin(__builtin_amdgcn_exp2f)
#define EXP2F(x) __builtin_amdgcn_exp2f(x)
#else
#define EXP2F(x) exp2f(x)
#endif

// sqrt(128) * log2(e): folded into w_theta/b_theta at wcvt time.
#define KSCALE 16.3222312f

#define NB 4
#define CH 256
#define CI 128
#define NS 4096   // 64*64 spatial
#define SPLIT 8

__device__ __forceinline__ unsigned short f2bf(float f) {
    unsigned int u = __builtin_bit_cast(unsigned int, f);
    u += 0x7fffu + ((u >> 16) & 1u);           // RNE
    return (unsigned short)(u >> 16);
}
__device__ __forceinline__ unsigned int pk2(float lo, float hi) {
    return (unsigned int)f2bf(lo) | ((unsigned int)f2bf(hi) << 16);
}
// truncating pack (softmax P only): 1-op v_perm_b32
__device__ __forceinline__ unsigned int pkt(float lo, float hi) {
    return __builtin_amdgcn_perm(__builtin_bit_cast(unsigned int, hi),
                                 __builtin_bit_cast(unsigned int, lo), 0x07060302u);
}
__device__ __forceinline__ float bf2f(unsigned int ush) {   // low 16 bits
    return __builtin_bit_cast(float, ush << 16);
}

// Half-exchange for P-fragment assembly (verified R3).
// Call as plswap(wLow, wHigh):
//   in : wLow  = even-g word, lane-half h holds s16 (4h+m0, 4h+m0+1)
//        wHigh = odd-g  word, lane-half h holds s16 (8+4h+m0, 8+4h+m0+1)
//   out: wLow  = fragment k-low word, wHigh = fragment k-high word
__device__ __forceinline__ void plswap(unsigned int& wLow, unsigned int& wHigh) {
    asm volatile("v_permlane32_swap_b32 %0, %1" : "+v"(wLow), "+v"(wHigh));
}

__device__ __forceinline__ f32x16 zero16() {
    f32x16 v;
#pragma unroll
    for (int i = 0; i < 16; i++) v[i] = 0.f;
    return v;
}

// async global->LDS 16B per lane: LDS dest = wave-uniform base + lane*16
__device__ __forceinline__ void gload16(void* lds, const void* g) {
    __builtin_amdgcn_global_load_lds(
        (const __attribute__((address_space(1))) unsigned int*)g,
        (__attribute__((address_space(3))) unsigned int*)lds,
        16, 0, 0);
}

// ---------------------------------------------------------------------------
// Kernel 0: one-time weight convert to bf16 (KSCALE folded into theta).
// ---------------------------------------------------------------------------
__global__ void wcvt_kernel(const float* __restrict__ w_g, const float* __restrict__ w_th,
                            const float* __restrict__ w_ph, const float* __restrict__ w_out,
                            const float* __restrict__ b_g, const float* __restrict__ b_th,
                            const float* __restrict__ b_ph,
                            unsigned short* __restrict__ wbf, float* __restrict__ bsc) {
    int i = blockIdx.x * 256 + threadIdx.x;     // 0..131071
    float v;
    if (i < 32768)        v = w_g[i];
    else if (i < 65536)   v = w_th[i - 32768] * KSCALE;
    else if (i < 98304)   v = w_ph[i - 65536];
    else                  v = w_out[i - 98304];
    wbf[i] = f2bf(v);
    if (i < 128)          bsc[i] = b_g[i];
    else if (i < 256)     bsc[i] = b_th[i - 128] * KSCALE;
    else if (i < 384)     bsc[i] = b_ph[i - 256];
}

// ---------------------------------------------------------------------------
// Kernel 1: FUSED projections — one x staging serves g/theta/phi (x read 1x).
// grid(64 s-tiles of 64, 4 n) = 256 blocks, 512 thr (8 waves).
// ---------------------------------------------------------------------------
__global__ __launch_bounds__(512, 2)
void proj_kernel(const float* __restrict__ x,
                 const unsigned short* __restrict__ wbf, const float* __restrict__ bsc,
                 unsigned short* __restrict__ theta,
                 unsigned short* __restrict__ phi,
                 unsigned short* __restrict__ gT) {
    const int tid  = threadIdx.x;
    const int wid  = tid >> 6;         // 0..7
    const int lane = tid & 63;
    const int quad = lane >> 4;
    const int l15  = lane & 15;
    const int stile = blockIdx.x;      // 0..63
    const int n     = blockIdx.y;
    const int s0    = stile * 64;

    const float* xN = x + (size_t)n * CH * NS;

    __shared__ unsigned int xp[64 * 128];   // 32 KB, swizzled

    // stage: 2048 tasks (128 c-pairs x 16 s-spans of float4), 4/thread
#pragma unroll
    for (int i = 0; i < 4; i++) {
        int t  = i * 512 + tid;
        int s4 = t & 15;
        int cp = t >> 4;                    // 0..127
        const float* p0 = xN + (size_t)(2 * cp) * NS + s0 + s4 * 4;
        float4 a = *(const float4*)p0;
        float4 b = *(const float4*)(p0 + NS);
        int col = (((cp >> 2) ^ (s4 & 7)) << 2) | (cp & 3);   // row>>2 == s4
        unsigned int* xr = xp + (s4 * 4) * 128 + col;
        xr[0]   = pk2(a.x, b.x);
        xr[128] = pk2(a.y, b.y);
        xr[256] = pk2(a.z, b.z);
        xr[384] = pk2(a.w, b.w);
    }
    __syncthreads();

    const int srow = (wid & 3) * 16 + l15;
    const int oh   = wid >> 2;              // o-half
    const int sw7  = (srow >> 2) & 7;
#pragma unroll
    for (int wi = 0; wi < 3; wi++) {
        f32x4 acc[4];
#pragma unroll
        for (int ot = 0; ot < 4; ot++) acc[ot] = (f32x4){0.f, 0.f, 0.f, 0.f};
        const unsigned short* W = wbf + (size_t)wi * 32768 + (size_t)oh * 64 * CH;
#pragma unroll
        for (int kc = 0; kc < 8; kc++) {
            bf16x8 af = *(const bf16x8*)(&xp[srow * 128 + (((kc * 4 + quad) ^ sw7) << 2)]);
#pragma unroll
            for (int ot = 0; ot < 4; ot++) {
                bf16x8 wf = *(const bf16x8*)(W + (size_t)(ot * 16 + l15) * CH + kc * 32 + quad * 8);
                acc[ot] = MFMA16(af, wf, acc[ot]);
            }
        }
        const float* Bv = bsc + wi * 128 + oh * 64;
#pragma unroll
        for (int ot = 0; ot < 4; ot++) {
            int o = oh * 64 + ot * 16 + l15;
            float bias = Bv[ot * 16 + l15];
#pragma unroll
            for (int r = 0; r < 4; r++) {
                int sg = s0 + (wid & 3) * 16 + quad * 4 + r;
                float v = acc[ot][r] + bias;
                if (wi == 0)
                    gT[((size_t)n * CI + o) * NS + sg] = f2bf(v);
                else if (wi == 1)
                    theta[((size_t)n * NS + sg) * CI + o] = f2bf(v);
                else
                    phi[((size_t)n * NS + sg) * CI + o] = f2bf(v);
            }
        }
    }
}

// ---------------------------------------------------------------------------
// Kernel 2: flash attention partials — R3 dataflow (K+V both LDS-staged via
// coalesced global_load_lds; V-direct was VMEM-scatter-bound, R5/R6) with an
// OCCUPANCY restructure:
//   * split 4->8  -> grid 1024 (4 blocks/CU schedulable; was grid-capped 2)
//   * V single-buffered, staged IN-CHUNK: issued after barrier1, consumed
//     after barrier2 (post-softmax) ~1300 cyc later — L2 latency hidden.
//     K stays double-buffered.  LDS 64->48 KB -> 3 blocks/CU.
//   * __launch_bounds__(256,3) pins regs <=170 so ~168-unified -> 3 waves/SIMD.
// Race safety: barrier1 = all waves done PV(ck-1) before V(ck) overwrite;
// barrier2's per-wave vmcnt drain = cross-wave V visibility before PV.
// grid(32 = split*4+n, 32 qb) = 1024 blocks, 256 thr.
// ---------------------------------------------------------------------------
__global__ __launch_bounds__(256, 3)
void attn_kernel(const unsigned short* __restrict__ theta,
                 const unsigned short* __restrict__ phi,
                 const unsigned short* __restrict__ gT,
                 unsigned short* __restrict__ Opart,
                 float* __restrict__ lbuf) {
    const int tid  = threadIdx.x;
    const int wid  = tid >> 6;          // 0..3
    const int lane = tid & 63;
    const int l31  = lane & 31;
    const int lh32 = lane >> 5;         // 0..1
    const int sn    = blockIdx.x;       // 0..31
    const int split = sn >> 2;          // 0..7
    const int n     = sn & 3;
    const int qb    = blockIdx.y;       // 0..31
    const int qbase = qb * 128 + wid * 32;

    const unsigned short* thN = theta + (size_t)n * NS * CI;
    const unsigned short* phN = phi   + (size_t)n * NS * CI;
    const unsigned short* gN  = gT    + (size_t)n * CI * NS;

    // K dbuf: 2 x [64 s][128 c] (slot ^ (s&15))   32 KB
    // V sbuf: 1 x [128 c][64 s] (slot ^ (c&7))    16 KB     total 48 KB
    __shared__ unsigned short smem[24576];
    unsigned short* Kb = smem;              // + cur*8192
    unsigned short* Vb = smem + 16384;

    // Q B-fragments: col = q = l31, k = lh32*8 + e within each 16-c slice
    bf16x8 qf[8];
#pragma unroll
    for (int kc = 0; kc < 8; kc++)
        qf[kc] = *(const bf16x8*)(thN + (size_t)(qbase + l31) * CI + kc * 16 + lh32 * 8);

    f32x16 O[4];    // O^T tiles: row c = ct*32 + (reg&3)+8*(reg>>2)+4*lh32, col q = l31
#pragma unroll
    for (int ct = 0; ct < 4; ct++) O[ct] = zero16();
    float lrun = 0.f;

    const int sbase0 = split * 512;
    const int lh16 = lane >> 4, lm16 = lane & 15;
    const int lh8  = lane >> 3, lm8  = lane & 7;

    // prologue: stage K chunk 0 -> buffer 0 (4 segs per wave)
#pragma unroll
    for (int i = 0; i < 4; i++) {
        int seg = wid * 4 + i;                  // 0..15
        int s   = seg * 4 + lh16;               // 0..63
        int j   = lm16 ^ (s & 15);
        gload16(Kb + seg * 512, phN + (size_t)(sbase0 + s) * CI + j * 8);
    }

    for (int ck = 0; ck < 8; ck++) {
        const int cur = ck & 1, nxt = cur ^ 1;
        unsigned short* Kc = Kb + cur * 8192;
        __syncthreads();    // barrier1: K(ck) visible; all waves done PV(ck-1)

        // stage V(ck) into the single V buffer (safe after barrier1)
        const int sb0 = sbase0 + ck * 64;
#pragma unroll
        for (int i = 0; i < 4; i++) {
            int seg = wid * 4 + i;
            int c   = seg * 8 + lh8;            // 0..127
            int j   = lm8 ^ (c & 7);
            gload16(Vb + seg * 512, gN + (size_t)c * NS + sb0 + j * 8);
        }
        if (ck + 1 < 8) {   // prefetch next K chunk into the other K buffer
            const int sb1 = sb0 + 64;
#pragma unroll
            for (int i = 0; i < 4; i++) {
                int seg = wid * 4 + i;
                int s   = seg * 4 + lh16;
                int j   = lm16 ^ (s & 15);
                gload16(Kb + nxt * 8192 + seg * 512, phN + (size_t)(sb1 + s) * CI + j * 8);
            }
        }
        __builtin_amdgcn_sched_barrier(0);   // pin staging issues above compute

        // QK^T -> S^T: interleaved S0/S1 chains, 8 c-slices
        f32x16 S0 = zero16(), S1 = zero16();
        __builtin_amdgcn_s_setprio(1);
#pragma unroll
        for (int kc = 0; kc < 8; kc++) {
            int s0r = l31;
            int s1r = 32 + l31;
            bf16x8 kf0 = *(const bf16x8*)(Kc + s0r * 128 + (((kc * 2 + lh32) ^ (s0r & 15)) * 8));
            bf16x8 kf1 = *(const bf16x8*)(Kc + s1r * 128 + (((kc * 2 + lh32) ^ (s1r & 15)) * 8));
            S0 = MFMA32(kf0, qf[kc], S0);
            S1 = MFMA32(kf1, qf[kc], S1);
        }
        __builtin_amdgcn_s_setprio(0);

        // softmax: p = exp2(S); assemble P B-fragments (k=s) per 16-s slice.
        bf16x8 pf[4];
        float lsum = 0.f;
#pragma unroll
        for (int ks = 0; ks < 4; ks++) {
            const f32x16& S = (ks < 2) ? S0 : S1;
            const int b = ks & 1;
            float pA[4], pB[4];
#pragma unroll
            for (int m = 0; m < 4; m++) {
                pA[m] = EXP2F(S[(2 * b) * 4 + m]);       // even g: s16 = m+4h
                pB[m] = EXP2F(S[(2 * b + 1) * 4 + m]);   // odd g:  s16 = 8+m+4h
            }
            lsum += ((pA[0] + pA[1]) + (pA[2] + pA[3]))
                  + ((pB[0] + pB[1]) + (pB[2] + pB[3]));
            unsigned int wA0 = pkt(pA[0], pA[1]);
            unsigned int wA1 = pkt(pA[2], pA[3]);
            unsigned int wB0 = pkt(pB[0], pB[1]);
            unsigned int wB1 = pkt(pB[2], pB[3]);
            plswap(wA0, wB0);   // wA0 -> u0, wB0 -> u2
            plswap(wA1, wB1);   // wA1 -> u1, wB1 -> u3
            union { unsigned int u[4]; bf16x8 v; } P;
            P.u[0] = wA0; P.u[1] = wA1; P.u[2] = wB0; P.u[3] = wB1;
            pf[ks] = P.v;
        }
        lrun += lsum;

        __syncthreads();    // barrier2: all waves' V(ck) loads drained+visible

        // PV: O^T += V^T . P^T over 4 K=16 slices (V from single LDS buffer)
        __builtin_amdgcn_s_setprio(1);
#pragma unroll
        for (int ks = 0; ks < 4; ks++) {
#pragma unroll
            for (int ct = 0; ct < 4; ct++) {
                int c = ct * 32 + l31;
                bf16x8 vf = *(const bf16x8*)(Vb + c * 64 + (((ks * 2 + lh32) ^ (c & 7)) * 8));
                O[ct] = MFMA32(vf, pf[ks], O[ct]);
            }
        }
        __builtin_amdgcn_s_setprio(0);
    }

    // epilogue: O^T (32x32 tiles) -> Opart[q][c] bf16 via per-wave LDS
    // transpose, 2 passes of 2 ct (8 KB tb per wave), XOR-swizzled 16B slots.
    __syncthreads();
    float* tb = (float*)smem + wid * 2048;   // 4 waves x 8 KB = 32 KB <= 48 KB
    const size_t obase = ((size_t)(split * NB + n)) * NS * CI;
#pragma unroll
    for (int pass = 0; pass < 2; pass++) {
#pragma unroll
        for (int cti = 0; cti < 2; cti++) {
            const int ct = pass * 2 + cti;
#pragma unroll
            for (int g = 0; g < 4; g++) {
                const int c_local = cti * 32 + 8 * g + 4 * lh32;   // +0..3
                const int slot = (c_local >> 2) ^ (l31 & 15);
                f32x4 v;
                v[0] = O[ct][4 * g + 0]; v[1] = O[ct][4 * g + 1];
                v[2] = O[ct][4 * g + 2]; v[3] = O[ct][4 * g + 3];
                *(f32x4*)(tb + l31 * 64 + slot * 4) = v;
            }
        }
#pragma unroll
        for (int i = 0; i < 8; i++) {
            const int qr  = i * 4 + (lane >> 4);    // 0..31
            const int lin = lane & 15;
            f32x4 v = *(const f32x4*)(tb + qr * 64 + ((lin ^ (qr & 15)) * 4));
            uint2 w;
            w.x = pk2(v[0], v[1]);
            w.y = pk2(v[2], v[3]);
            *(uint2*)(Opart + obase + (size_t)(qbase + qr) * CI + pass * 64 + lin * 4) = w;
        }
        __syncthreads();   // tb region reused across passes
    }
    lrun += __shfl_xor(lrun, 32);
    if (lane < 32)
        lbuf[(split * NB + n) * NS + qbase + l31] = lrun;
}

// ---------------------------------------------------------------------------
// Kernel 3: fused merge (8 bf16 partials) + output projection + residual.
// grid(64 s-tiles, 2 o-halves, 4 n) = 512 blocks, 256 thr.
// ---------------------------------------------------------------------------
__global__ __launch_bounds__(256, 4)
void outproj_kernel(const float* __restrict__ x,
                    const unsigned short* __restrict__ wbf,
                    const float* __restrict__ b_out,
                    const unsigned short* __restrict__ Opart,
                    const float* __restrict__ lbuf,
                    float* __restrict__ out) {
    const int tid  = threadIdx.x;
    const int wid  = tid >> 6;
    const int lane = tid & 63;
    const int quad = lane >> 4;
    const int l15  = lane & 15;
    const int oh = blockIdx.y;
    const int n  = blockIdx.z;
    const int sw = blockIdx.x * 64 + wid * 16;
    const int T  = NB * NS;

    const int srow = n * NS + sw + l15;
    float l = 0.f;
#pragma unroll
    for (int k = 0; k < SPLIT; k++) l += lbuf[k * T + srow];
    float rinv = 1.0f / l;

    bf16x8 yb[4];
#pragma unroll
    for (int kc = 0; kc < 4; kc++) {
        float f0 = 0.f, f1 = 0.f, f2 = 0.f, f3 = 0.f;
        float f4 = 0.f, f5 = 0.f, f6 = 0.f, f7 = 0.f;
#pragma unroll
        for (int k = 0; k < SPLIT; k++) {
            uint4 v = *(const uint4*)(Opart + ((size_t)k * T + srow) * CI + kc * 32 + quad * 8);
            f0 += bf2f(v.x & 0xffffu); f1 += bf2f(v.x >> 16);
            f2 += bf2f(v.y & 0xffffu); f3 += bf2f(v.y >> 16);
            f4 += bf2f(v.z & 0xffffu); f5 += bf2f(v.z >> 16);
            f6 += bf2f(v.w & 0xffffu); f7 += bf2f(v.w >> 16);
        }
        union { unsigned int uu[4]; bf16x8 vv; } r;
        r.uu[0] = pk2(f0 * rinv, f1 * rinv);
        r.uu[1] = pk2(f2 * rinv, f3 * rinv);
        r.uu[2] = pk2(f4 * rinv, f5 * rinv);
        r.uu[3] = pk2(f6 * rinv, f7 * rinv);
        yb[kc] = r.vv;
    }

    const unsigned short* wob = wbf + 3 * 32768 + (size_t)oh * 128 * CI;
    f32x4 acc[8];
#pragma unroll
    for (int ot = 0; ot < 8; ot++) acc[ot] = (f32x4){0.f, 0.f, 0.f, 0.f};
#pragma unroll
    for (int kc = 0; kc < 4; kc++) {
#pragma unroll
        for (int ot = 0; ot < 8; ot++) {
            bf16x8 wa = *(const bf16x8*)(wob + (size_t)(ot * 16 + l15) * CI + kc * 32 + quad * 8);
            acc[ot] = MFMA16(wa, yb[kc], acc[ot]);
        }
    }
#pragma unroll
    for (int ot = 0; ot < 8; ot++) {
#pragma unroll
        for (int r = 0; r < 4; r++) {
            int o = oh * 128 + ot * 16 + quad * 4 + r;
            size_t idx = ((size_t)n * CH + o) * NS + sw + l15;
            out[idx] = x[idx] + acc[ot][r] + b_out[o];
        }
    }
}

// ---------------------------------------------------------------------------
extern "C" void kernel_launch(void* const* d_in, const int* in_sizes, int n_in,
                              void* d_out, int out_size, void* d_ws, size_t ws_size,
                              hipStream_t stream) {
    const float* x     = (const float*)d_in[0];
    const float* w_g   = (const float*)d_in[1];
    const float* b_g   = (const float*)d_in[2];
    const float* w_th  = (const float*)d_in[3];
    const float* b_th  = (const float*)d_in[4];
    const float* w_ph  = (const float*)d_in[5];
    const float* b_ph  = (const float*)d_in[6];
    const float* w_out = (const float*)d_in[7];
    const float* b_out = (const float*)d_in[8];
    float* out = (float*)d_out;

    char* ws = (char*)d_ws;
    unsigned short* theta = (unsigned short*)(ws + 0);          //  4 MiB
    unsigned short* phi   = (unsigned short*)(ws + 4194304);    //  4 MiB
    unsigned short* gT    = (unsigned short*)(ws + 8388608);    //  4 MiB
    unsigned short* Opart = (unsigned short*)(ws + 12582912);   // 32 MiB (8 splits bf16)
    float* lbuf  = (float*)(ws + 46137344);                     // 512 KiB
    unsigned short* wbf = (unsigned short*)(ws + 46661632);     // 256 KiB
    float* bsc   = (float*)(ws + 46923776);                     //  1.5 KiB

    wcvt_kernel<<<512, 256, 0, stream>>>(w_g, w_th, w_ph, w_out, b_g, b_th, b_ph, wbf, bsc);
    proj_kernel<<<dim3(64, NB), 512, 0, stream>>>(x, wbf, bsc, theta, phi, gT);
    attn_kernel<<<dim3(32, 32), 256, 0, stream>>>(theta, phi, gT, Opart, lbuf);
    outproj_kernel<<<dim3(64, 2, NB), 256, 0, stream>>>(x, wbf, b_out, Opart, lbuf, out);
}

// Round 8
// 178.318 us; speedup vs baseline: 1.1768x; 1.0911x over previous
//
#include <hip/hip_runtime.h>
#include <cmath>

typedef __attribute__((ext_vector_type(8))) short bf16x8;
typedef __attribute__((ext_vector_type(4))) float f32x4;
typedef __attribute__((ext_vector_type(16))) float f32x16;

#define MFMA16(a,b,c)  __builtin_amdgcn_mfma_f32_16x16x32_bf16((a),(b),(c),0,0,0)
#define MFMA32(a,b,c)  __builtin_amdgcn_mfma_f32_32x32x16_bf16((a),(b),(c),0,0,0)

#if __has_builtin(__builtin_amdgcn_exp2f)
#define EXP2F(x) __builtin_amdgcn_exp2f(x)
#else
#define EXP2F(x) exp2f(x)
#endif

// sqrt(128) * log2(e): folded into w_theta/b_theta at wcvt time.
#define KSCALE 16.3222312f

#define NB 4
#define CH 256
#define CI 128
#define NS 4096   // 64*64 spatial
#define SPLIT 8

__device__ __forceinline__ unsigned short f2bf(float f) {
    unsigned int u = __builtin_bit_cast(unsigned int, f);
    u += 0x7fffu + ((u >> 16) & 1u);           // RNE
    return (unsigned short)(u >> 16);
}
__device__ __forceinline__ unsigned int pk2(float lo, float hi) {
    return (unsigned int)f2bf(lo) | ((unsigned int)f2bf(hi) << 16);
}
// truncating pack (softmax P only): 1-op v_perm_b32
__device__ __forceinline__ unsigned int pkt(float lo, float hi) {
    return __builtin_amdgcn_perm(__builtin_bit_cast(unsigned int, hi),
                                 __builtin_bit_cast(unsigned int, lo), 0x07060302u);
}
__device__ __forceinline__ float bf2f(unsigned int ush) {   // low 16 bits
    return __builtin_bit_cast(float, ush << 16);
}

// Half-exchange for P-fragment assembly (verified R3).
// Call as plswap(wLow, wHigh):
//   in : wLow  = even-g word, lane-half h holds s16 (4h+m0, 4h+m0+1)
//        wHigh = odd-g  word, lane-half h holds s16 (8+4h+m0, 8+4h+m0+1)
//   out: wLow  = fragment k-low word, wHigh = fragment k-high word
__device__ __forceinline__ void plswap(unsigned int& wLow, unsigned int& wHigh) {
    asm volatile("v_permlane32_swap_b32 %0, %1" : "+v"(wLow), "+v"(wHigh));
}

__device__ __forceinline__ f32x16 zero16() {
    f32x16 v;
#pragma unroll
    for (int i = 0; i < 16; i++) v[i] = 0.f;
    return v;
}

// async global->LDS 16B per lane: LDS dest = wave-uniform base + lane*16
__device__ __forceinline__ void gload16(void* lds, const void* g) {
    __builtin_amdgcn_global_load_lds(
        (const __attribute__((address_space(1))) unsigned int*)g,
        (__attribute__((address_space(3))) unsigned int*)lds,
        16, 0, 0);
}

// ---------------------------------------------------------------------------
// Kernel 0: one-time weight convert to bf16 (KSCALE folded into theta).
// ---------------------------------------------------------------------------
__global__ void wcvt_kernel(const float* __restrict__ w_g, const float* __restrict__ w_th,
                            const float* __restrict__ w_ph, const float* __restrict__ w_out,
                            const float* __restrict__ b_g, const float* __restrict__ b_th,
                            const float* __restrict__ b_ph,
                            unsigned short* __restrict__ wbf, float* __restrict__ bsc) {
    int i = blockIdx.x * 256 + threadIdx.x;     // 0..131071
    float v;
    if (i < 32768)        v = w_g[i];
    else if (i < 65536)   v = w_th[i - 32768] * KSCALE;
    else if (i < 98304)   v = w_ph[i - 65536];
    else                  v = w_out[i - 98304];
    wbf[i] = f2bf(v);
    if (i < 128)          bsc[i] = b_g[i];
    else if (i < 256)     bsc[i] = b_th[i - 128] * KSCALE;
    else if (i < 384)     bsc[i] = b_ph[i - 256];
}

// ---------------------------------------------------------------------------
// Kernel 1: FUSED projections — one x staging serves g/theta/phi (x read 1x).
// grid(64 s-tiles of 64, 4 n) = 256 blocks, 512 thr (8 waves).
// ---------------------------------------------------------------------------
__global__ __launch_bounds__(512, 2)
void proj_kernel(const float* __restrict__ x,
                 const unsigned short* __restrict__ wbf, const float* __restrict__ bsc,
                 unsigned short* __restrict__ theta,
                 unsigned short* __restrict__ phi,
                 unsigned short* __restrict__ gT) {
    const int tid  = threadIdx.x;
    const int wid  = tid >> 6;         // 0..7
    const int lane = tid & 63;
    const int quad = lane >> 4;
    const int l15  = lane & 15;
    const int stile = blockIdx.x;      // 0..63
    const int n     = blockIdx.y;
    const int s0    = stile * 64;

    const float* xN = x + (size_t)n * CH * NS;

    __shared__ unsigned int xp[64 * 128];   // 32 KB, swizzled

    // stage: 2048 tasks (128 c-pairs x 16 s-spans of float4), 4/thread
#pragma unroll
    for (int i = 0; i < 4; i++) {
        int t  = i * 512 + tid;
        int s4 = t & 15;
        int cp = t >> 4;                    // 0..127
        const float* p0 = xN + (size_t)(2 * cp) * NS + s0 + s4 * 4;
        float4 a = *(const float4*)p0;
        float4 b = *(const float4*)(p0 + NS);
        int col = (((cp >> 2) ^ (s4 & 7)) << 2) | (cp & 3);   // row>>2 == s4
        unsigned int* xr = xp + (s4 * 4) * 128 + col;
        xr[0]   = pk2(a.x, b.x);
        xr[128] = pk2(a.y, b.y);
        xr[256] = pk2(a.z, b.z);
        xr[384] = pk2(a.w, b.w);
    }
    __syncthreads();

    const int srow = (wid & 3) * 16 + l15;
    const int oh   = wid >> 2;              // o-half
    const int sw7  = (srow >> 2) & 7;
#pragma unroll
    for (int wi = 0; wi < 3; wi++) {
        f32x4 acc[4];
#pragma unroll
        for (int ot = 0; ot < 4; ot++) acc[ot] = (f32x4){0.f, 0.f, 0.f, 0.f};
        const unsigned short* W = wbf + (size_t)wi * 32768 + (size_t)oh * 64 * CH;
#pragma unroll
        for (int kc = 0; kc < 8; kc++) {
            bf16x8 af = *(const bf16x8*)(&xp[srow * 128 + (((kc * 4 + quad) ^ sw7) << 2)]);
#pragma unroll
            for (int ot = 0; ot < 4; ot++) {
                bf16x8 wf = *(const bf16x8*)(W + (size_t)(ot * 16 + l15) * CH + kc * 32 + quad * 8);
                acc[ot] = MFMA16(af, wf, acc[ot]);
            }
        }
        const float* Bv = bsc + wi * 128 + oh * 64;
#pragma unroll
        for (int ot = 0; ot < 4; ot++) {
            int o = oh * 64 + ot * 16 + l15;
            float bias = Bv[ot * 16 + l15];
#pragma unroll
            for (int r = 0; r < 4; r++) {
                int sg = s0 + (wid & 3) * 16 + quad * 4 + r;
                float v = acc[ot][r] + bias;
                if (wi == 0)
                    gT[((size_t)n * CI + o) * NS + sg] = f2bf(v);
                else if (wi == 1)
                    theta[((size_t)n * NS + sg) * CI + o] = f2bf(v);
                else
                    phi[((size_t)n * NS + sg) * CI + o] = f2bf(v);
            }
        }
    }
}

// ---------------------------------------------------------------------------
// Kernel 2: flash attention partials — R7 occupancy plan with the register
// working set SHRUNK so 3 waves/SIMD actually fits (R7 spilled: FETCH/WRITE
// ballooned).  Per 32-s sub-block processing: S = ONE f32x16, pf = 2 frags.
// Working set: O 64 (AGPR) + qf 32 + S 16 + pf 8 + temps ~ 145 <= 170.
// Chunk schedule: barrier1 -> stage V(ck) + prefetch K(ck+1) ->
//   QK^T(sb0) -> softmax(sb0) -> barrier2 (V visible) -> PV(ks0,1) ->
//   QK^T(sb1) -> softmax(sb1) -> PV(ks2,3).
// K dbuf 32 KB + V sbuf 16 KB = 48 KB -> 3 blocks/CU; split=8, grid 1024.
// grid(32 = split*4+n, 32 qb) = 1024 blocks, 256 thr.
// ---------------------------------------------------------------------------
__global__ __launch_bounds__(256, 3)
void attn_kernel(const unsigned short* __restrict__ theta,
                 const unsigned short* __restrict__ phi,
                 const unsigned short* __restrict__ gT,
                 unsigned short* __restrict__ Opart,
                 float* __restrict__ lbuf) {
    const int tid  = threadIdx.x;
    const int wid  = tid >> 6;          // 0..3
    const int lane = tid & 63;
    const int l31  = lane & 31;
    const int lh32 = lane >> 5;         // 0..1
    const int sn    = blockIdx.x;       // 0..31
    const int split = sn >> 2;          // 0..7
    const int n     = sn & 3;
    const int qb    = blockIdx.y;       // 0..31
    const int qbase = qb * 128 + wid * 32;

    const unsigned short* thN = theta + (size_t)n * NS * CI;
    const unsigned short* phN = phi   + (size_t)n * NS * CI;
    const unsigned short* gN  = gT    + (size_t)n * CI * NS;

    // K dbuf: 2 x [64 s][128 c] (slot ^ (s&15))   32 KB
    // V sbuf: 1 x [128 c][64 s] (slot ^ (c&7))    16 KB     total 48 KB
    __shared__ unsigned short smem[24576];
    unsigned short* Kb = smem;              // + cur*8192
    unsigned short* Vb = smem + 16384;

    // Q B-fragments: col = q = l31, k = lh32*8 + e within each 16-c slice
    bf16x8 qf[8];
#pragma unroll
    for (int kc = 0; kc < 8; kc++)
        qf[kc] = *(const bf16x8*)(thN + (size_t)(qbase + l31) * CI + kc * 16 + lh32 * 8);

    f32x16 O[4];    // O^T tiles: row c = ct*32 + (reg&3)+8*(reg>>2)+4*lh32, col q = l31
#pragma unroll
    for (int ct = 0; ct < 4; ct++) O[ct] = zero16();
    float lrun = 0.f;

    const int sbase0 = split * 512;
    const int lh16 = lane >> 4, lm16 = lane & 15;
    const int lh8  = lane >> 3, lm8  = lane & 7;

    // prologue: stage K chunk 0 -> buffer 0 (4 segs per wave)
#pragma unroll
    for (int i = 0; i < 4; i++) {
        int seg = wid * 4 + i;                  // 0..15
        int s   = seg * 4 + lh16;               // 0..63
        int j   = lm16 ^ (s & 15);
        gload16(Kb + seg * 512, phN + (size_t)(sbase0 + s) * CI + j * 8);
    }

    for (int ck = 0; ck < 8; ck++) {
        const int cur = ck & 1, nxt = cur ^ 1;
        unsigned short* Kc = Kb + cur * 8192;
        __syncthreads();    // barrier1: K(ck) visible; all waves done PV(ck-1)

        // stage V(ck) into the single V buffer (safe after barrier1)
        const int sb0g = sbase0 + ck * 64;
#pragma unroll
        for (int i = 0; i < 4; i++) {
            int seg = wid * 4 + i;
            int c   = seg * 8 + lh8;            // 0..127
            int j   = lm8 ^ (c & 7);
            gload16(Vb + seg * 512, gN + (size_t)c * NS + sb0g + j * 8);
        }
        if (ck + 1 < 8) {   // prefetch next K chunk into the other K buffer
            const int sb1g = sb0g + 64;
#pragma unroll
            for (int i = 0; i < 4; i++) {
                int seg = wid * 4 + i;
                int s   = seg * 4 + lh16;
                int j   = lm16 ^ (s & 15);
                gload16(Kb + nxt * 8192 + seg * 512, phN + (size_t)(sb1g + s) * CI + j * 8);
            }
        }
        __builtin_amdgcn_sched_barrier(0);   // pin staging issues above compute

        // ---- two 32-s sub-blocks, each fully processed (S lives per-sb) ----
#pragma unroll
        for (int sb = 0; sb < 2; sb++) {
            // QK^T for this sub-block: 8 c-slices into one accumulator
            f32x16 S = zero16();
            const int sr = sb * 32 + l31;
            __builtin_amdgcn_s_setprio(1);
#pragma unroll
            for (int kc = 0; kc < 8; kc++) {
                bf16x8 kf = *(const bf16x8*)(Kc + sr * 128 + (((kc * 2 + lh32) ^ (sr & 15)) * 8));
                S = MFMA32(kf, qf[kc], S);
            }
            __builtin_amdgcn_s_setprio(0);

            // softmax: p = exp2(S); P B-fragments (k=s) for the 2 16-s slices
            bf16x8 pf[2];
            float lsum = 0.f;
#pragma unroll
            for (int b = 0; b < 2; b++) {
                float pA[4], pB[4];
#pragma unroll
                for (int m = 0; m < 4; m++) {
                    pA[m] = EXP2F(S[(2 * b) * 4 + m]);       // even g: s16 = m+4h
                    pB[m] = EXP2F(S[(2 * b + 1) * 4 + m]);   // odd g:  s16 = 8+m+4h
                }
                lsum += ((pA[0] + pA[1]) + (pA[2] + pA[3]))
                      + ((pB[0] + pB[1]) + (pB[2] + pB[3]));
                unsigned int wA0 = pkt(pA[0], pA[1]);
                unsigned int wA1 = pkt(pA[2], pA[3]);
                unsigned int wB0 = pkt(pB[0], pB[1]);
                unsigned int wB1 = pkt(pB[2], pB[3]);
                plswap(wA0, wB0);   // wA0 -> u0, wB0 -> u2
                plswap(wA1, wB1);   // wA1 -> u1, wB1 -> u3
                union { unsigned int u[4]; bf16x8 v; } P;
                P.u[0] = wA0; P.u[1] = wA1; P.u[2] = wB0; P.u[3] = wB1;
                pf[b] = P.v;
            }
            lrun += lsum;

            if (sb == 0)
                __syncthreads();    // barrier2: all waves' V(ck) loads visible

            // PV for this sub-block: ks = sb*2 + b
            __builtin_amdgcn_s_setprio(1);
#pragma unroll
            for (int b = 0; b < 2; b++) {
                const int ks = sb * 2 + b;
#pragma unroll
                for (int ct = 0; ct < 4; ct++) {
                    int c = ct * 32 + l31;
                    bf16x8 vf = *(const bf16x8*)(Vb + c * 64 + (((ks * 2 + lh32) ^ (c & 7)) * 8));
                    O[ct] = MFMA32(vf, pf[b], O[ct]);
                }
            }
            __builtin_amdgcn_s_setprio(0);
        }
    }

    // epilogue: O^T (32x32 tiles) -> Opart[q][c] bf16 via per-wave LDS
    // transpose, 2 passes of 2 ct (8 KB tb per wave), XOR-swizzled 16B slots.
    __syncthreads();
    float* tb = (float*)smem + wid * 2048;   // 4 waves x 8 KB = 32 KB <= 48 KB
    const size_t obase = ((size_t)(split * NB + n)) * NS * CI;
#pragma unroll
    for (int pass = 0; pass < 2; pass++) {
#pragma unroll
        for (int cti = 0; cti < 2; cti++) {
            const int ct = pass * 2 + cti;
#pragma unroll
            for (int g = 0; g < 4; g++) {
                const int c_local = cti * 32 + 8 * g + 4 * lh32;   // +0..3
                const int slot = (c_local >> 2) ^ (l31 & 15);
                f32x4 v;
                v[0] = O[ct][4 * g + 0]; v[1] = O[ct][4 * g + 1];
                v[2] = O[ct][4 * g + 2]; v[3] = O[ct][4 * g + 3];
                *(f32x4*)(tb + l31 * 64 + slot * 4) = v;
            }
        }
#pragma unroll
        for (int i = 0; i < 8; i++) {
            const int qr  = i * 4 + (lane >> 4);    // 0..31
            const int lin = lane & 15;
            f32x4 v = *(const f32x4*)(tb + qr * 64 + ((lin ^ (qr & 15)) * 4));
            uint2 w;
            w.x = pk2(v[0], v[1]);
            w.y = pk2(v[2], v[3]);
            *(uint2*)(Opart + obase + (size_t)(qbase + qr) * CI + pass * 64 + lin * 4) = w;
        }
        __syncthreads();   // tb region reused across passes
    }
    lrun += __shfl_xor(lrun, 32);
    if (lane < 32)
        lbuf[(split * NB + n) * NS + qbase + l31] = lrun;
}

// ---------------------------------------------------------------------------
// Kernel 3: fused merge (8 bf16 partials) + output projection + residual.
// grid(64 s-tiles, 2 o-halves, 4 n) = 512 blocks, 256 thr.
// ---------------------------------------------------------------------------
__global__ __launch_bounds__(256, 4)
void outproj_kernel(const float* __restrict__ x,
                    const unsigned short* __restrict__ wbf,
                    const float* __restrict__ b_out,
                    const unsigned short* __restrict__ Opart,
                    const float* __restrict__ lbuf,
                    float* __restrict__ out) {
    const int tid  = threadIdx.x;
    const int wid  = tid >> 6;
    const int lane = tid & 63;
    const int quad = lane >> 4;
    const int l15  = lane & 15;
    const int oh = blockIdx.y;
    const int n  = blockIdx.z;
    const int sw = blockIdx.x * 64 + wid * 16;
    const int T  = NB * NS;

    const int srow = n * NS + sw + l15;
    float l = 0.f;
#pragma unroll
    for (int k = 0; k < SPLIT; k++) l += lbuf[k * T + srow];
    float rinv = 1.0f / l;

    bf16x8 yb[4];
#pragma unroll
    for (int kc = 0; kc < 4; kc++) {
        float f0 = 0.f, f1 = 0.f, f2 = 0.f, f3 = 0.f;
        float f4 = 0.f, f5 = 0.f, f6 = 0.f, f7 = 0.f;
#pragma unroll
        for (int k = 0; k < SPLIT; k++) {
            uint4 v = *(const uint4*)(Opart + ((size_t)k * T + srow) * CI + kc * 32 + quad * 8);
            f0 += bf2f(v.x & 0xffffu); f1 += bf2f(v.x >> 16);
            f2 += bf2f(v.y & 0xffffu); f3 += bf2f(v.y >> 16);
            f4 += bf2f(v.z & 0xffffu); f5 += bf2f(v.z >> 16);
            f6 += bf2f(v.w & 0xffffu); f7 += bf2f(v.w >> 16);
        }
        union { unsigned int uu[4]; bf16x8 vv; } r;
        r.uu[0] = pk2(f0 * rinv, f1 * rinv);
        r.uu[1] = pk2(f2 * rinv, f3 * rinv);
        r.uu[2] = pk2(f4 * rinv, f5 * rinv);
        r.uu[3] = pk2(f6 * rinv, f7 * rinv);
        yb[kc] = r.vv;
    }

    const unsigned short* wob = wbf + 3 * 32768 + (size_t)oh * 128 * CI;
    f32x4 acc[8];
#pragma unroll
    for (int ot = 0; ot < 8; ot++) acc[ot] = (f32x4){0.f, 0.f, 0.f, 0.f};
#pragma unroll
    for (int kc = 0; kc < 4; kc++) {
#pragma unroll
        for (int ot = 0; ot < 8; ot++) {
            bf16x8 wa = *(const bf16x8*)(wob + (size_t)(ot * 16 + l15) * CI + kc * 32 + quad * 8);
            acc[ot] = MFMA16(wa, yb[kc], acc[ot]);
        }
    }
#pragma unroll
    for (int ot = 0; ot < 8; ot++) {
#pragma unroll
        for (int r = 0; r < 4; r++) {
            int o = oh * 128 + ot * 16 + quad * 4 + r;
            size_t idx = ((size_t)n * CH + o) * NS + sw + l15;
            out[idx] = x[idx] + acc[ot][r] + b_out[o];
        }
    }
}

// ---------------------------------------------------------------------------
extern "C" void kernel_launch(void* const* d_in, const int* in_sizes, int n_in,
                              void* d_out, int out_size, void* d_ws, size_t ws_size,
                              hipStream_t stream) {
    const float* x     = (const float*)d_in[0];
    const float* w_g   = (const float*)d_in[1];
    const float* b_g   = (const float*)d_in[2];
    const float* w_th  = (const float*)d_in[3];
    const float* b_th  = (const float*)d_in[4];
    const float* w_ph  = (const float*)d_in[5];
    const float* b_ph  = (const float*)d_in[6];
    const float* w_out = (const float*)d_in[7];
    const float* b_out = (const float*)d_in[8];
    float* out = (float*)d_out;

    char* ws = (char*)d_ws;
    unsigned short* theta = (unsigned short*)(ws + 0);          //  4 MiB
    unsigned short* phi   = (unsigned short*)(ws + 4194304);    //  4 MiB
    unsigned short* gT    = (unsigned short*)(ws + 8388608);    //  4 MiB
    unsigned short* Opart = (unsigned short*)(ws + 12582912);   // 32 MiB (8 splits bf16)
    float* lbuf  = (float*)(ws + 46137344);                     // 512 KiB
    unsigned short* wbf = (unsigned short*)(ws + 46661632);     // 256 KiB
    float* bsc   = (float*)(ws + 46923776);                     //  1.5 KiB

    wcvt_kernel<<<512, 256, 0, stream>>>(w_g, w_th, w_ph, w_out, b_g, b_th, b_ph, wbf, bsc);
    proj_kernel<<<dim3(64, NB), 512, 0, stream>>>(x, wbf, bsc, theta, phi, gT);
    attn_kernel<<<dim3(32, 32), 256, 0, stream>>>(theta, phi, gT, Opart, lbuf);
    outproj_kernel<<<dim3(64, 2, NB), 256, 0, stream>>>(x, wbf, b_out, Opart, lbuf, out);
}

// Round 9
// 144.317 us; speedup vs baseline: 1.4541x; 1.2356x over previous
//
#include <hip/hip_runtime.h>
#include <cmath>

typedef __attribute__((ext_vector_type(8))) short bf16x8;
typedef __attribute__((ext_vector_type(4))) float f32x4;
typedef __attribute__((ext_vector_type(16))) float f32x16;

#define MFMA16(a,b,c)  __builtin_amdgcn_mfma_f32_16x16x32_bf16((a),(b),(c),0,0,0)
#define MFMA32(a,b,c)  __builtin_amdgcn_mfma_f32_32x32x16_bf16((a),(b),(c),0,0,0)

#if __has_builtin(__builtin_amdgcn_exp2f)
#define EXP2F(x) __builtin_amdgcn_exp2f(x)
#else
#define EXP2F(x) exp2f(x)
#endif

// sqrt(128) * log2(e): folded into w_theta/b_theta at wcvt time.
#define KSCALE 16.3222312f

#define NB 4
#define CH 256
#define CI 128
#define NS 4096   // 64*64 spatial

__device__ __forceinline__ unsigned short f2bf(float f) {
    unsigned int u = __builtin_bit_cast(unsigned int, f);
    u += 0x7fffu + ((u >> 16) & 1u);           // RNE
    return (unsigned short)(u >> 16);
}
__device__ __forceinline__ unsigned int pk2(float lo, float hi) {
    return (unsigned int)f2bf(lo) | ((unsigned int)f2bf(hi) << 16);
}
// truncating pack (softmax P only): 1-op v_perm_b32
__device__ __forceinline__ unsigned int pkt(float lo, float hi) {
    return __builtin_amdgcn_perm(__builtin_bit_cast(unsigned int, hi),
                                 __builtin_bit_cast(unsigned int, lo), 0x07060302u);
}
__device__ __forceinline__ float bf2f(unsigned int ush) {   // low 16 bits
    return __builtin_bit_cast(float, ush << 16);
}

// Half-exchange for P-fragment assembly (verified R3).
__device__ __forceinline__ void plswap(unsigned int& wLow, unsigned int& wHigh) {
    asm volatile("v_permlane32_swap_b32 %0, %1" : "+v"(wLow), "+v"(wHigh));
}

__device__ __forceinline__ f32x16 zero16() {
    f32x16 v;
#pragma unroll
    for (int i = 0; i < 16; i++) v[i] = 0.f;
    return v;
}

// async global->LDS 16B per lane: LDS dest = wave-uniform base + lane*16
__device__ __forceinline__ void gload16(void* lds, const void* g) {
    __builtin_amdgcn_global_load_lds(
        (const __attribute__((address_space(1))) unsigned int*)g,
        (__attribute__((address_space(3))) unsigned int*)lds,
        16, 0, 0);
}

// ---------------------------------------------------------------------------
// Kernel 0: one-time weight convert to bf16, written in MFMA-FRAGMENT ORDER
// so the hot kernels' weight loads are coalesced (lane*16B contiguous):
//   proj   : wbf[(wi*2+oh)*16384 + kc*2048 + ot*512 + lane*8 + e]
//            = w[wi][o = oh*64 + ot*16 + (lane&15)][c = kc*32 + (lane>>4)*8 + e]
//   outproj: wbf[98304 + oh*16384 + kc*4096 + ot*512 + lane*8 + e]
//            = w_out[o = oh*128 + ot*16 + (lane&15)][c = kc*32 + (lane>>4)*8 + e]
// (old layout made 16 lanes stride 512B -> 16 cache-line requests per load.)
// ---------------------------------------------------------------------------
__global__ void wcvt_kernel(const float* __restrict__ w_g, const float* __restrict__ w_th,
                            const float* __restrict__ w_ph, const float* __restrict__ w_out,
                            const float* __restrict__ b_g, const float* __restrict__ b_th,
                            const float* __restrict__ b_ph,
                            unsigned short* __restrict__ wbf, float* __restrict__ bsc) {
    int i = blockIdx.x * 256 + threadIdx.x;     // 0..131071
    float v;
    if (i < 98304) {
        int wi = i >> 15;             // 0 g, 1 theta, 2 phi
        int r  = i & 32767;
        int oh = r >> 14;
        int r2 = r & 16383;
        int kc = r2 >> 11;            // 0..7
        int r3 = r2 & 2047;
        int ot = r3 >> 9;             // 0..3
        int r4 = r3 & 511;
        int lane = r4 >> 3;           // 0..63
        int e  = r4 & 7;
        int o = oh * 64 + ot * 16 + (lane & 15);
        int c = kc * 32 + (lane >> 4) * 8 + e;
        const float* W = (wi == 0) ? w_g : (wi == 1 ? w_th : w_ph);
        v = W[o * CH + c];
        if (wi == 1) v *= KSCALE;
    } else {
        int r = i - 98304;
        int oh = r >> 14;
        int r2 = r & 16383;
        int kc = r2 >> 12;            // 0..3
        int r3 = r2 & 4095;
        int ot = r3 >> 9;             // 0..7
        int r4 = r3 & 511;
        int lane = r4 >> 3;
        int e = r4 & 7;
        int o = oh * 128 + ot * 16 + (lane & 15);
        int c = kc * 32 + (lane >> 4) * 8 + e;
        v = w_out[o * CI + c];
    }
    wbf[i] = f2bf(v);
    if (i < 128)          bsc[i] = b_g[i];
    else if (i < 256)     bsc[i] = b_th[i - 128] * KSCALE;
    else if (i < 384)     bsc[i] = b_ph[i - 256];
}

// ---------------------------------------------------------------------------
// Kernel 1: FUSED projections — one x staging serves g/theta/phi (x read 1x).
// grid(64 s-tiles of 64, 4 n) = 256 blocks, 512 thr (8 waves).
// Weight loads now fragment-ordered (coalesced 1KB/inst); gT stores packed
// as uint2 (r=0..3 are 4 consecutive s for fixed o).
// ---------------------------------------------------------------------------
__global__ __launch_bounds__(512, 2)
void proj_kernel(const float* __restrict__ x,
                 const unsigned short* __restrict__ wbf, const float* __restrict__ bsc,
                 unsigned short* __restrict__ theta,
                 unsigned short* __restrict__ phi,
                 unsigned short* __restrict__ gT) {
    const int tid  = threadIdx.x;
    const int wid  = tid >> 6;         // 0..7
    const int lane = tid & 63;
    const int quad = lane >> 4;
    const int l15  = lane & 15;
    const int stile = blockIdx.x;      // 0..63
    const int n     = blockIdx.y;
    const int s0    = stile * 64;

    const float* xN = x + (size_t)n * CH * NS;

    __shared__ unsigned int xp[64 * 128];   // 32 KB, swizzled

    // stage: 2048 tasks (128 c-pairs x 16 s-spans of float4), 4/thread
#pragma unroll
    for (int i = 0; i < 4; i++) {
        int t  = i * 512 + tid;
        int s4 = t & 15;
        int cp = t >> 4;                    // 0..127
        const float* p0 = xN + (size_t)(2 * cp) * NS + s0 + s4 * 4;
        float4 a = *(const float4*)p0;
        float4 b = *(const float4*)(p0 + NS);
        int col = (((cp >> 2) ^ (s4 & 7)) << 2) | (cp & 3);   // row>>2 == s4
        unsigned int* xr = xp + (s4 * 4) * 128 + col;
        xr[0]   = pk2(a.x, b.x);
        xr[128] = pk2(a.y, b.y);
        xr[256] = pk2(a.z, b.z);
        xr[384] = pk2(a.w, b.w);
    }
    __syncthreads();

    const int srow = (wid & 3) * 16 + l15;
    const int oh   = wid >> 2;              // o-half
    const int sw7  = (srow >> 2) & 7;
#pragma unroll
    for (int wi = 0; wi < 3; wi++) {
        f32x4 acc[4];
#pragma unroll
        for (int ot = 0; ot < 4; ot++) acc[ot] = (f32x4){0.f, 0.f, 0.f, 0.f};
        const unsigned short* W = wbf + (size_t)(wi * 2 + oh) * 16384;
#pragma unroll
        for (int kc = 0; kc < 8; kc++) {
            bf16x8 af = *(const bf16x8*)(&xp[srow * 128 + (((kc * 4 + quad) ^ sw7) << 2)]);
#pragma unroll
            for (int ot = 0; ot < 4; ot++) {
                bf16x8 wf = *(const bf16x8*)(W + kc * 2048 + ot * 512 + lane * 8);
                acc[ot] = MFMA16(af, wf, acc[ot]);
            }
        }
        const float* Bv = bsc + wi * 128 + oh * 64;
#pragma unroll
        for (int ot = 0; ot < 4; ot++) {
            int o = oh * 64 + ot * 16 + l15;
            float bias = Bv[ot * 16 + l15];
            if (wi == 0) {
                // gT[o][s]: r=0..3 are consecutive s -> pack uint2 (4 bf16)
                int sg0 = s0 + (wid & 3) * 16 + quad * 4;
                uint2 w;
                w.x = pk2(acc[ot][0] + bias, acc[ot][1] + bias);
                w.y = pk2(acc[ot][2] + bias, acc[ot][3] + bias);
                *(uint2*)(gT + (size_t)((size_t)n * CI + o) * NS + sg0) = w;
            } else {
#pragma unroll
                for (int r = 0; r < 4; r++) {
                    int sg = s0 + (wid & 3) * 16 + quad * 4 + r;
                    float v = acc[ot][r] + bias;
                    if (wi == 1)
                        theta[((size_t)n * NS + sg) * CI + o] = f2bf(v);
                    else
                        phi[((size_t)n * NS + sg) * CI + o] = f2bf(v);
                }
            }
        }
    }
}

// ---------------------------------------------------------------------------
// Kernel 2: flash attention partials — R3-exact structure (measured 45.2us).
// 256 thr (4 waves), q=32/wave, 64-s chunks, K/V double-buffer, 64 KB LDS,
// split=4.  grid(16 = split*4+n, 32 qb) = 512 blocks.
// ---------------------------------------------------------------------------
__global__ __launch_bounds__(256, 2)
void attn_kernel(const unsigned short* __restrict__ theta,
                 const unsigned short* __restrict__ phi,
                 const unsigned short* __restrict__ gT,
                 unsigned short* __restrict__ Opart,
                 float* __restrict__ lbuf) {
    const int tid  = threadIdx.x;
    const int wid  = tid >> 6;          // 0..3
    const int lane = tid & 63;
    const int l31  = lane & 31;
    const int lh32 = lane >> 5;         // 0..1
    const int sn    = blockIdx.x;       // 0..15
    const int split = sn >> 2;          // 0..3
    const int n     = sn & 3;
    const int qb    = blockIdx.y;       // 0..31
    const int qbase = qb * 128 + wid * 32;

    const unsigned short* thN = theta + (size_t)n * NS * CI;
    const unsigned short* phN = phi   + (size_t)n * NS * CI;
    const unsigned short* gN  = gT    + (size_t)n * CI * NS;

    // K dbuf: 2 x [64 s][128 c] (slot ^ (s&15))   32 KB
    // V dbuf: 2 x [128 c][64 s] (slot ^ (c&7))    32 KB     total 64 KB
    __shared__ unsigned short smem[32768];
    unsigned short* Kb = smem;              // + cur*8192
    unsigned short* Vb = smem + 16384;      // + cur*8192

    // Q B-fragments: col = q = l31, k = lh32*8 + e within each 16-c slice
    bf16x8 qf[8];
#pragma unroll
    for (int kc = 0; kc < 8; kc++)
        qf[kc] = *(const bf16x8*)(thN + (size_t)(qbase + l31) * CI + kc * 16 + lh32 * 8);

    f32x16 O[4];    // O^T tiles: row c = ct*32 + (reg&3)+8*(reg>>2)+4*lh32, col q = l31
#pragma unroll
    for (int ct = 0; ct < 4; ct++) O[ct] = zero16();
    float lrun = 0.f;

    const int sbase0 = split * 1024;
    const int lh16 = lane >> 4, lm16 = lane & 15;
    const int lh8  = lane >> 3, lm8  = lane & 7;

    // stage chunk 0 -> buffer 0 (4 K segs + 4 V segs per wave)
#pragma unroll
    for (int i = 0; i < 4; i++) {
        int seg = wid * 4 + i;                  // 0..15
        int s   = seg * 4 + lh16;               // 0..63
        int j   = lm16 ^ (s & 15);
        gload16(Kb + seg * 512, phN + (size_t)(sbase0 + s) * CI + j * 8);
    }
#pragma unroll
    for (int i = 0; i < 4; i++) {
        int seg = wid * 4 + i;
        int c   = seg * 8 + lh8;                // 0..127
        int j   = lm8 ^ (c & 7);
        gload16(Vb + seg * 512, gN + (size_t)c * NS + sbase0 + j * 8);
    }

    for (int ck = 0; ck < 16; ck++) {
        const int cur = ck & 1, nxt = cur ^ 1;
        unsigned short* Kc = Kb + cur * 8192;
        unsigned short* Vc = Vb + cur * 8192;
        __syncthreads();    // drains cur loads; prev compute done

        if (ck + 1 < 16) {  // async prefetch next chunk
            const int sb1 = sbase0 + (ck + 1) * 64;
#pragma unroll
            for (int i = 0; i < 4; i++) {
                int seg = wid * 4 + i;
                int s   = seg * 4 + lh16;
                int j   = lm16 ^ (s & 15);
                gload16(Kb + nxt * 8192 + seg * 512, phN + (size_t)(sb1 + s) * CI + j * 8);
            }
#pragma unroll
            for (int i = 0; i < 4; i++) {
                int seg = wid * 4 + i;
                int c   = seg * 8 + lh8;
                int j   = lm8 ^ (c & 7);
                gload16(Vb + nxt * 8192 + seg * 512, gN + (size_t)c * NS + sb1 + j * 8);
            }
        }

        // QK^T -> S^T: 2 s-blocks x 8 c-slices
        f32x16 S[2];
        S[0] = zero16(); S[1] = zero16();
        __builtin_amdgcn_s_setprio(1);
#pragma unroll
        for (int sb = 0; sb < 2; sb++) {
#pragma unroll
            for (int kc = 0; kc < 8; kc++) {
                int s = sb * 32 + l31;
                bf16x8 kf = *(const bf16x8*)(Kc + s * 128 + (((kc * 2 + lh32) ^ (s & 15)) * 8));
                S[sb] = MFMA32(kf, qf[kc], S[sb]);
            }
        }
        __builtin_amdgcn_s_setprio(0);

        // softmax: p = exp2(S); assemble P B-fragments (k=s) per 16-s slice.
        bf16x8 pf[4];
        float lsum = 0.f;
#pragma unroll
        for (int ks = 0; ks < 4; ks++) {
            const int sb = ks >> 1, b = ks & 1;
            float pA[4], pB[4];
#pragma unroll
            for (int m = 0; m < 4; m++) {
                pA[m] = EXP2F(S[sb][(2 * b) * 4 + m]);       // even g: s16 = m+4h
                pB[m] = EXP2F(S[sb][(2 * b + 1) * 4 + m]);   // odd g:  s16 = 8+m+4h
            }
            lsum += ((pA[0] + pA[1]) + (pA[2] + pA[3]))
                  + ((pB[0] + pB[1]) + (pB[2] + pB[3]));
            unsigned int wA0 = pkt(pA[0], pA[1]);
            unsigned int wA1 = pkt(pA[2], pA[3]);
            unsigned int wB0 = pkt(pB[0], pB[1]);
            unsigned int wB1 = pkt(pB[2], pB[3]);
            plswap(wA0, wB0);   // wA0 -> u0, wB0 -> u2
            plswap(wA1, wB1);   // wA1 -> u1, wB1 -> u3
            union { unsigned int u[4]; bf16x8 v; } P;
            P.u[0] = wA0; P.u[1] = wA1; P.u[2] = wB0; P.u[3] = wB1;
            pf[ks] = P.v;
        }
        lrun += lsum;

        // PV: O^T += V^T . P^T over 4 K=16 slices (P from registers).
        __builtin_amdgcn_s_setprio(1);
#pragma unroll
        for (int ks = 0; ks < 4; ks++) {
#pragma unroll
            for (int ct = 0; ct < 4; ct++) {
                int c = ct * 32 + l31;
                bf16x8 vf = *(const bf16x8*)(Vc + c * 64 + (((ks * 2 + lh32) ^ (c & 7)) * 8));
                O[ct] = MFMA32(vf, pf[ks], O[ct]);
            }
        }
        __builtin_amdgcn_s_setprio(0);
    }

    // epilogue: O^T (32x32 tiles) -> Opart[q][c] bf16 via per-wave LDS
    // transpose, 2 passes of 2 ct (8 KB tb per wave), XOR-swizzled 16B slots.
    __syncthreads();
    float* tb = (float*)smem + wid * 2048;   // 4 waves x 8 KB
    const size_t obase = ((size_t)(split * NB + n)) * NS * CI;
#pragma unroll
    for (int pass = 0; pass < 2; pass++) {
#pragma unroll
        for (int cti = 0; cti < 2; cti++) {
            const int ct = pass * 2 + cti;
#pragma unroll
            for (int g = 0; g < 4; g++) {
                const int c_local = cti * 32 + 8 * g + 4 * lh32;   // +0..3
                const int slot = (c_local >> 2) ^ (l31 & 15);
                f32x4 v;
                v[0] = O[ct][4 * g + 0]; v[1] = O[ct][4 * g + 1];
                v[2] = O[ct][4 * g + 2]; v[3] = O[ct][4 * g + 3];
                *(f32x4*)(tb + l31 * 64 + slot * 4) = v;
            }
        }
#pragma unroll
        for (int i = 0; i < 8; i++) {
            const int qr  = i * 4 + (lane >> 4);    // 0..31
            const int lin = lane & 15;
            f32x4 v = *(const f32x4*)(tb + qr * 64 + ((lin ^ (qr & 15)) * 4));
            uint2 w;
            w.x = pk2(v[0], v[1]);
            w.y = pk2(v[2], v[3]);
            *(uint2*)(Opart + obase + (size_t)(qbase + qr) * CI + pass * 64 + lin * 4) = w;
        }
    }
    lrun += __shfl_xor(lrun, 32);
    if (lane < 32)
        lbuf[(split * NB + n) * NS + qbase + l31] = lrun;
}

// ---------------------------------------------------------------------------
// Kernel 3: fused merge (4 bf16 partials) + output projection + residual.
// grid(64 s-tiles, 2 o-halves, 4 n) = 512 blocks, 256 thr.
// Weight loads fragment-ordered (coalesced).
// ---------------------------------------------------------------------------
__global__ __launch_bounds__(256, 4)
void outproj_kernel(const float* __restrict__ x,
                    const unsigned short* __restrict__ wbf,
                    const float* __restrict__ b_out,
                    const unsigned short* __restrict__ Opart,
                    const float* __restrict__ lbuf,
                    float* __restrict__ out) {
    const int tid  = threadIdx.x;
    const int wid  = tid >> 6;
    const int lane = tid & 63;
    const int quad = lane >> 4;
    const int l15  = lane & 15;
    const int oh = blockIdx.y;
    const int n  = blockIdx.z;
    const int sw = blockIdx.x * 64 + wid * 16;
    const int T  = NB * NS;

    const int srow = n * NS + sw + l15;
    float l = 0.f;
#pragma unroll
    for (int k = 0; k < 4; k++) l += lbuf[k * T + srow];
    float rinv = 1.0f / l;

    bf16x8 yb[4];
#pragma unroll
    for (int kc = 0; kc < 4; kc++) {
        float f0 = 0.f, f1 = 0.f, f2 = 0.f, f3 = 0.f;
        float f4 = 0.f, f5 = 0.f, f6 = 0.f, f7 = 0.f;
#pragma unroll
        for (int k = 0; k < 4; k++) {
            uint4 v = *(const uint4*)(Opart + ((size_t)k * T + srow) * CI + kc * 32 + quad * 8);
            f0 += bf2f(v.x & 0xffffu); f1 += bf2f(v.x >> 16);
            f2 += bf2f(v.y & 0xffffu); f3 += bf2f(v.y >> 16);
            f4 += bf2f(v.z & 0xffffu); f5 += bf2f(v.z >> 16);
            f6 += bf2f(v.w & 0xffffu); f7 += bf2f(v.w >> 16);
        }
        union { unsigned int uu[4]; bf16x8 vv; } r;
        r.uu[0] = pk2(f0 * rinv, f1 * rinv);
        r.uu[1] = pk2(f2 * rinv, f3 * rinv);
        r.uu[2] = pk2(f4 * rinv, f5 * rinv);
        r.uu[3] = pk2(f6 * rinv, f7 * rinv);
        yb[kc] = r.vv;
    }

    const unsigned short* wof = wbf + 98304 + (size_t)oh * 16384;
    f32x4 acc[8];
#pragma unroll
    for (int ot = 0; ot < 8; ot++) acc[ot] = (f32x4){0.f, 0.f, 0.f, 0.f};
#pragma unroll
    for (int kc = 0; kc < 4; kc++) {
#pragma unroll
        for (int ot = 0; ot < 8; ot++) {
            bf16x8 wa = *(const bf16x8*)(wof + kc * 4096 + ot * 512 + lane * 8);
            acc[ot] = MFMA16(wa, yb[kc], acc[ot]);
        }
    }
#pragma unroll
    for (int ot = 0; ot < 8; ot++) {
#pragma unroll
        for (int r = 0; r < 4; r++) {
            int o = oh * 128 + ot * 16 + quad * 4 + r;
            size_t idx = ((size_t)n * CH + o) * NS + sw + l15;
            out[idx] = x[idx] + acc[ot][r] + b_out[o];
        }
    }
}

// ---------------------------------------------------------------------------
extern "C" void kernel_launch(void* const* d_in, const int* in_sizes, int n_in,
                              void* d_out, int out_size, void* d_ws, size_t ws_size,
                              hipStream_t stream) {
    const float* x     = (const float*)d_in[0];
    const float* w_g   = (const float*)d_in[1];
    const float* b_g   = (const float*)d_in[2];
    const float* w_th  = (const float*)d_in[3];
    const float* b_th  = (const float*)d_in[4];
    const float* w_ph  = (const float*)d_in[5];
    const float* b_ph  = (const float*)d_in[6];
    const float* w_out = (const float*)d_in[7];
    const float* b_out = (const float*)d_in[8];
    float* out = (float*)d_out;

    char* ws = (char*)d_ws;
    unsigned short* theta = (unsigned short*)(ws + 0);          //  4 MiB
    unsigned short* phi   = (unsigned short*)(ws + 4194304);    //  4 MiB
    unsigned short* gT    = (unsigned short*)(ws + 8388608);    //  4 MiB
    unsigned short* Opart = (unsigned short*)(ws + 12582912);   // 16 MiB (4 splits bf16)
    float* lbuf  = (float*)(ws + 29360128);                     // 256 KiB
    unsigned short* wbf = (unsigned short*)(ws + 29622272);     // 256 KiB
    float* bsc   = (float*)(ws + 29884416);                     //  1.5 KiB

    wcvt_kernel<<<512, 256, 0, stream>>>(w_g, w_th, w_ph, w_out, b_g, b_th, b_ph, wbf, bsc);
    proj_kernel<<<dim3(64, NB), 512, 0, stream>>>(x, wbf, bsc, theta, phi, gT);
    attn_kernel<<<dim3(16, 32), 256, 0, stream>>>(theta, phi, gT, Opart, lbuf);
    outproj_kernel<<<dim3(64, 2, NB), 256, 0, stream>>>(x, wbf, b_out, Opart, lbuf, out);
}